// Round 2
// baseline (1735.853 us; speedup 1.0000x reference)
//
#include <hip/hip_runtime.h>
#include <hip/hip_bf16.h>

#define N_NODES 100000
#define N_EDGES 1600000
#define IN_F    128
#define HH      3      // heads
#define DD      16     // out feats per head
#define HD      48     // HH*DD
#define NEG_SLOPE 0.2f
#define EPS_V   1e-9f

__device__ __forceinline__ float leaky(float x) { return x >= 0.f ? x : NEG_SLOPE * x; }

// monotonic float<->uint encoding for atomicMax on floats
__device__ __forceinline__ unsigned fenc(float f) {
    unsigned u = __float_as_uint(f);
    return (u & 0x80000000u) ? ~u : (u | 0x80000000u);
}
__device__ __forceinline__ float fdec(unsigned u) {
    u = (u & 0x80000000u) ? (u & 0x7FFFFFFFu) : ~u;
    return __uint_as_float(u);
}

// ---------------- GEMM: ft[N,48] = feat[N,128] @ W[128,48] ----------------
#define GR 32
__global__ __launch_bounds__(256) void k_gemm(const float* __restrict__ feat,
                                              const float* __restrict__ W,
                                              float* __restrict__ ft) {
    __shared__ float Ws[IN_F][HD];        // 24 KB
    __shared__ float Fs[GR][IN_F + 1];    // padded: avoid bank conflict
    int t = threadIdx.x;
    for (int i = t; i < IN_F * HD; i += 256) Ws[i / HD][i % HD] = W[i];
    int row0 = blockIdx.x * GR;
    for (int i = t; i < GR * IN_F; i += 256) {
        int r = i >> 7, c = i & 127;
        int gr = row0 + r;
        Fs[r][c] = (gr < N_NODES) ? feat[gr * IN_F + c] : 0.f;
    }
    __syncthreads();
    int r = t >> 3;      // 0..31
    int cg = t & 7;      // 0..7 -> cols 6*cg .. 6*cg+5
    float acc[6] = {0, 0, 0, 0, 0, 0};
    for (int k = 0; k < IN_F; ++k) {
        float a = Fs[r][k];
#pragma unroll
        for (int j = 0; j < 6; ++j) acc[j] += a * Ws[k][cg * 6 + j];
    }
    int gr = row0 + r;
    if (gr < N_NODES) {
#pragma unroll
        for (int j = 0; j < 6; ++j) ft[gr * HD + cg * 6 + j] = acc[j];
    }
}

// ---------------- el/er: per (n,h) dot with attn vectors ----------------
__global__ void k_eler(const float* __restrict__ ft, const float* __restrict__ attn_l,
                       const float* __restrict__ attn_r, float* __restrict__ el,
                       float* __restrict__ er) {
    int i = blockIdx.x * blockDim.x + threadIdx.x;  // n*3+h
    if (i >= N_NODES * HH) return;
    int h = i % HH;
    float sl = 0.f, sr = 0.f;
#pragma unroll
    for (int d = 0; d < DD; ++d) {
        float v = ft[i * DD + d];
        sl += v * attn_l[h * DD + d];
        sr += v * attn_r[h * DD + d];
    }
    el[i] = sl;
    er[i] = sr;
}

// ---------------- degree histogram ----------------
__global__ void k_hist(const int* __restrict__ dst, int* __restrict__ deg) {
    int e = blockIdx.x * blockDim.x + threadIdx.x;
    if (e < N_EDGES) atomicAdd(&deg[dst[e]], 1);
}

// ---------------- exclusive scan (single block, 1024 thr, 8 elems/thr) ----------------
__global__ __launch_bounds__(1024) void k_scan(const int* __restrict__ deg,
                                               int* __restrict__ rowstart) {
    __shared__ int wsum[16];
    __shared__ int s_carry;
    int t = threadIdx.x, lane = t & 63, w = t >> 6;
    if (t == 0) s_carry = 0;
    __syncthreads();
    const int CHUNK = 8192;
    for (int base = 0; base < N_NODES; base += CHUNK) {
        int v[8];
        int idx0 = base + t * 8;
#pragma unroll
        for (int j = 0; j < 8; ++j) {
            int id = idx0 + j;
            v[j] = (id < N_NODES) ? deg[id] : 0;
        }
#pragma unroll
        for (int j = 1; j < 8; ++j) v[j] += v[j - 1];
        int tsum = v[7];
        int sc = tsum;
#pragma unroll
        for (int off = 1; off < 64; off <<= 1) {
            int u = __shfl_up(sc, off, 64);
            if (lane >= off) sc += u;
        }
        if (lane == 63) wsum[w] = sc;
        __syncthreads();
        int wpre = 0;
        for (int j = 0; j < w; ++j) wpre += wsum[j];
        int thread_excl = s_carry + wpre + (sc - tsum);
#pragma unroll
        for (int j = 0; j < 8; ++j) {
            int id = idx0 + j;
            if (id < N_NODES) rowstart[id] = thread_excl + (j ? v[j - 1] : 0);
        }
        __syncthreads();
        if (t == 1023) s_carry += wpre + sc;
        __syncthreads();
    }
    if (threadIdx.x == 0) rowstart[N_NODES] = s_carry;
}

// ---------------- scatter into CSR order + segment-max atomics ----------------
__global__ void k_scatter(const int* __restrict__ src, const int* __restrict__ dst,
                          const int* __restrict__ rowstart, int* __restrict__ fillcnt,
                          int* __restrict__ perm_pos, int* __restrict__ src_sorted,
                          const float* __restrict__ el, const float* __restrict__ er,
                          unsigned* __restrict__ mdst, unsigned* __restrict__ msrc) {
    int e = blockIdx.x * blockDim.x + threadIdx.x;
    if (e >= N_EDGES) return;
    int s = src[e], d = dst[e];
    int p = rowstart[d] + atomicAdd(&fillcnt[d], 1);
    perm_pos[e] = p;
    src_sorted[p] = s;
#pragma unroll
    for (int h = 0; h < HH; ++h) {
        float sc = leaky(el[s * HH + h] + er[d * HH + h]);
        unsigned en = fenc(sc);
        atomicMax(&mdst[d * HH + h], en);
        atomicMax(&msrc[s * HH + h], en);
    }
}

// ---------------- exp-sum atomics ----------------
__global__ void k_expsum(const int* __restrict__ src, const int* __restrict__ dst,
                         const float* __restrict__ el, const float* __restrict__ er,
                         const unsigned* __restrict__ mdst, const unsigned* __restrict__ msrc,
                         float* __restrict__ sdst, float* __restrict__ ssrc) {
    int e = blockIdx.x * blockDim.x + threadIdx.x;
    if (e >= N_EDGES) return;
    int s = src[e], d = dst[e];
#pragma unroll
    for (int h = 0; h < HH; ++h) {
        float sc = leaky(el[s * HH + h] + er[d * HH + h]);
        atomicAdd(&sdst[d * HH + h], expf(sc - fdec(mdst[d * HH + h])));
        atomicAdd(&ssrc[s * HH + h], expf(sc - fdec(msrc[s * HH + h])));
    }
}

// ---------------- final attention coefficient, stored in CSR (dst-sorted) order ---------
__global__ void k_attn(const int* __restrict__ src, const int* __restrict__ dst,
                       const float* __restrict__ el, const float* __restrict__ er,
                       const unsigned* __restrict__ mdst, const unsigned* __restrict__ msrc,
                       const float* __restrict__ sdst, const float* __restrict__ ssrc,
                       const int* __restrict__ perm_pos, float* __restrict__ a_sorted) {
    int e = blockIdx.x * blockDim.x + threadIdx.x;
    if (e >= N_EDGES) return;
    int s = src[e], d = dst[e];
    int p = perm_pos[e];
#pragma unroll
    for (int h = 0; h < HH; ++h) {
        float sc = leaky(el[s * HH + h] + er[d * HH + h]);
        float ad = expf(sc - fdec(mdst[d * HH + h])) / sdst[d * HH + h];
        float as_ = expf(sc - fdec(msrc[s * HH + h])) / ssrc[s * HH + h];
        ad = fmaxf(ad, EPS_V);
        as_ = fmaxf(as_, EPS_V);
        a_sorted[p * HH + h] = sqrtf(ad * as_);
    }
}

// ---------------- one diffusion hop: out[n,h,:] = sum_edges a * cur[src,h,:] -----------
__global__ __launch_bounds__(256) void k_hop(const float* __restrict__ cur,
                                             const float* __restrict__ a_sorted,
                                             const int* __restrict__ rowstart,
                                             const int* __restrict__ src_sorted,
                                             float* __restrict__ out) {
    int wid = threadIdx.x >> 6, lane = threadIdx.x & 63;
    int n = blockIdx.x * 4 + wid;
    if (n >= N_NODES) return;
    if (lane >= HD) return;
    int h = lane >> 4;
    int rs = rowstart[n], re = rowstart[n + 1];
    float acc = 0.f;
    for (int p = rs; p < re; ++p) {
        int s = src_sorted[p];
        float a = a_sorted[p * HH + h];
        acc += a * cur[s * HD + lane];
    }
    out[n * HD + lane] = acc;
}

// ---------------- feat_trans + hop attention + output ----------------
__global__ void k_final(const float* __restrict__ ft, const float* __restrict__ cur1,
                        const float* __restrict__ cur2, const float* __restrict__ cur3,
                        const float* __restrict__ hop_l, const float* __restrict__ hop_r,
                        const float* __restrict__ pos_emb, const float* __restrict__ scales,
                        const float* __restrict__ offs, const float* __restrict__ bias,
                        float* __restrict__ out) {
    int i = blockIdx.x * blockDim.x + threadIdx.x;  // n*3+h
    if (i >= N_NODES * HH) return;
    int h = i % HH;
    const float* rows[4] = {ft + (size_t)i * DD, cur1 + (size_t)i * DD,
                            cur2 + (size_t)i * DD, cur3 + (size_t)i * DD};
    float hk[4][DD];
#pragma unroll
    for (int k = 0; k < 4; ++k) {
        float x[DD];
        float m = 0.f;
#pragma unroll
        for (int d = 0; d < DD; ++d) {
            x[d] = rows[k][d];
            m += x[d];
        }
        m *= (1.f / DD);
        float v2 = 0.f;
#pragma unroll
        for (int d = 0; d < DD; ++d) {
            float c = x[d] - m;
            v2 += c * c;
        }
        v2 = v2 * (1.f / DD) + EPS_V;
        float rs = rsqrtf(v2);
#pragma unroll
        for (int d = 0; d < DD; ++d) {
            hk[k][d] = (x[d] - m) * scales[k * HD + h * DD + d] * rs +
                       offs[k * HD + h * DD + d] + pos_emb[h * 64 + k * DD + d];
        }
    }
    float al = 0.f;
#pragma unroll
    for (int d = 0; d < DD; ++d) al += hk[0][d] * hop_l[h * DD + d];
    float ar[3], mx = -1e30f;
#pragma unroll
    for (int k = 0; k < 3; ++k) {
        float s = 0.f;
#pragma unroll
        for (int d = 0; d < DD; ++d) s += hk[k + 1][d] * hop_r[h * DD + d];
        ar[k] = leaky(s + al);
        mx = fmaxf(mx, ar[k]);
    }
    float den = 0.f, wgt[3];
#pragma unroll
    for (int k = 0; k < 3; ++k) {
        wgt[k] = expf(ar[k] - mx);
        den += wgt[k];
    }
#pragma unroll
    for (int k = 0; k < 3; ++k) wgt[k] /= den;
#pragma unroll
    for (int d = 0; d < DD; ++d) {
        float o = hk[1][d] * wgt[0] + hk[2][d] * wgt[1] + hk[3][d] * wgt[2] +
                  bias[h * DD + d];
        out[i * DD + d] = o;
    }
}

// ---------------- workspace layout (element offsets, 4 B units) ----------------
#define OFF_FT    0u          // 4.8M f32
#define OFF_EL    4800000u    // 300k
#define OFF_ER    5100000u    // 300k
#define OFF_DEG   5400000u    // 100k int   -- zeroed region starts here
#define OFF_FILL  5500000u    // 100k int
#define OFF_MDST  5600000u    // 300k uint
#define OFF_MSRC  5900000u    // 300k uint
#define OFF_SDST  6200000u    // 300k f32
#define OFF_SSRC  6500000u    // 300k f32   -- zeroed region ends at 6.8M
#define OFF_ROWS  6800000u    // 100001 int
#define OFF_PERM  6900008u    // 1.6M int
#define OFF_SSORT 8500008u    // 1.6M int
#define OFF_ASORT 10100008u   // 4.8M f32
#define OFF_CUR1  14900008u   // 4.8M f32
#define OFF_CUR2  19700008u
#define OFF_CUR3  24500008u
#define WS_FLOATS 29300008u

extern "C" void kernel_launch(void* const* d_in, const int* in_sizes, int n_in,
                              void* d_out, int out_size, void* d_ws, size_t ws_size,
                              hipStream_t stream) {
    if (ws_size < (size_t)WS_FLOATS * 4) return;  // insufficient scratch

    const float* feat   = (const float*)d_in[0];
    const int*   src    = (const int*)d_in[1];
    const int*   dst    = (const int*)d_in[2];
    const float* fc_W   = (const float*)d_in[3];
    const float* attn_l = (const float*)d_in[4];
    const float* attn_r = (const float*)d_in[5];
    const float* hop_l  = (const float*)d_in[6];
    const float* hop_r  = (const float*)d_in[7];
    const float* pos    = (const float*)d_in[8];
    const float* scal   = (const float*)d_in[9];
    const float* offs   = (const float*)d_in[10];
    const float* bias   = (const float*)d_in[11];
    float* out = (float*)d_out;

    float* ws = (float*)d_ws;
    float*    ft       = ws + OFF_FT;
    float*    el       = ws + OFF_EL;
    float*    er       = ws + OFF_ER;
    int*      deg      = (int*)(ws + OFF_DEG);
    int*      fillcnt  = (int*)(ws + OFF_FILL);
    unsigned* mdst     = (unsigned*)(ws + OFF_MDST);
    unsigned* msrc     = (unsigned*)(ws + OFF_MSRC);
    float*    sdst     = ws + OFF_SDST;
    float*    ssrc     = ws + OFF_SSRC;
    int*      rowstart = (int*)(ws + OFF_ROWS);
    int*      perm     = (int*)(ws + OFF_PERM);
    int*      ssort    = (int*)(ws + OFF_SSORT);
    float*    a_sorted = ws + OFF_ASORT;
    float*    cur1     = ws + OFF_CUR1;
    float*    cur2     = ws + OFF_CUR2;
    float*    cur3     = ws + OFF_CUR3;

    // zero accumulator region (deg..ssrc, contiguous 1.4M elems)
    hipMemsetAsync(ws + OFF_DEG, 0, (size_t)(OFF_ROWS - OFF_DEG) * 4, stream);

    k_gemm<<<(N_NODES + GR - 1) / GR, 256, 0, stream>>>(feat, fc_W, ft);
    k_eler<<<(N_NODES * HH + 255) / 256, 256, 0, stream>>>(ft, attn_l, attn_r, el, er);
    k_hist<<<(N_EDGES + 255) / 256, 256, 0, stream>>>(dst, deg);
    k_scan<<<1, 1024, 0, stream>>>(deg, rowstart);
    k_scatter<<<(N_EDGES + 255) / 256, 256, 0, stream>>>(src, dst, rowstart, fillcnt,
                                                         perm, ssort, el, er, mdst, msrc);
    k_expsum<<<(N_EDGES + 255) / 256, 256, 0, stream>>>(src, dst, el, er, mdst, msrc,
                                                        sdst, ssrc);
    k_attn<<<(N_EDGES + 255) / 256, 256, 0, stream>>>(src, dst, el, er, mdst, msrc,
                                                      sdst, ssrc, perm, a_sorted);
    k_hop<<<(N_NODES + 3) / 4, 256, 0, stream>>>(ft, a_sorted, rowstart, ssort, cur1);
    k_hop<<<(N_NODES + 3) / 4, 256, 0, stream>>>(cur1, a_sorted, rowstart, ssort, cur2);
    k_hop<<<(N_NODES + 3) / 4, 256, 0, stream>>>(cur2, a_sorted, rowstart, ssort, cur3);
    k_final<<<(N_NODES * HH + 255) / 256, 256, 0, stream>>>(ft, cur1, cur2, cur3, hop_l,
                                                            hop_r, pos, scal, offs, bias,
                                                            out);
}

// Round 3
// 1135.408 us; speedup vs baseline: 1.5288x; 1.5288x over previous
//
#include <hip/hip_runtime.h>
#include <hip/hip_bf16.h>

#define N_NODES 100000
#define N_EDGES 1600000
#define IN_F    128
#define HH      3      // heads
#define DD      16     // out feats per head
#define HD      48     // HH*DD
#define NEG_SLOPE 0.2f
#define EPS_V   1e-9f

__device__ __forceinline__ float leaky(float x) { return x >= 0.f ? x : NEG_SLOPE * x; }

// ---------------- GEMM: ft[N,48] = feat[N,128] @ W[128,48] ----------------
#define GR 32
__global__ __launch_bounds__(256) void k_gemm(const float* __restrict__ feat,
                                              const float* __restrict__ W,
                                              float* __restrict__ ft) {
    __shared__ float Ws[IN_F][HD];        // 24 KB
    __shared__ float Fs[GR][IN_F + 1];
    int t = threadIdx.x;
    for (int i = t; i < IN_F * HD; i += 256) Ws[i / HD][i % HD] = W[i];
    int row0 = blockIdx.x * GR;
    for (int i = t; i < GR * IN_F; i += 256) {
        int r = i >> 7, c = i & 127;
        int gr = row0 + r;
        Fs[r][c] = (gr < N_NODES) ? feat[gr * IN_F + c] : 0.f;
    }
    __syncthreads();
    int r = t >> 3, cg = t & 7;
    float acc[6] = {0, 0, 0, 0, 0, 0};
    for (int k = 0; k < IN_F; ++k) {
        float a = Fs[r][k];
#pragma unroll
        for (int j = 0; j < 6; ++j) acc[j] += a * Ws[k][cg * 6 + j];
    }
    int gr = row0 + r;
    if (gr < N_NODES) {
#pragma unroll
        for (int j = 0; j < 6; ++j) ft[gr * HD + cg * 6 + j] = acc[j];
    }
}

// ---------------- el/er ----------------
__global__ void k_eler(const float* __restrict__ ft, const float* __restrict__ attn_l,
                       const float* __restrict__ attn_r, float* __restrict__ el,
                       float* __restrict__ er) {
    int i = blockIdx.x * blockDim.x + threadIdx.x;
    if (i >= N_NODES * HH) return;
    int h = i % HH;
    float sl = 0.f, sr = 0.f;
#pragma unroll
    for (int d = 0; d < DD; ++d) {
        float v = ft[i * DD + d];
        sl += v * attn_l[h * DD + d];
        sr += v * attn_r[h * DD + d];
    }
    el[i] = sl;
    er[i] = sr;
}

// ---------------- degree histograms (both directions) ----------------
__global__ void k_hist(const int* __restrict__ src, const int* __restrict__ dst,
                       int* __restrict__ deg_s, int* __restrict__ deg_d) {
    int e = blockIdx.x * blockDim.x + threadIdx.x;
    if (e < N_EDGES) {
        atomicAdd(&deg_d[dst[e]], 1);
        atomicAdd(&deg_s[src[e]], 1);
    }
}

// ---------------- exclusive scan; block 0 scans dst-deg, block 1 scans src-deg ---------
__global__ __launch_bounds__(1024) void k_scan2(const int* __restrict__ deg_d,
                                                int* __restrict__ rows_d,
                                                const int* __restrict__ deg_s,
                                                int* __restrict__ rows_s) {
    const int* deg = blockIdx.x ? deg_s : deg_d;
    int* rowstart = blockIdx.x ? rows_s : rows_d;
    __shared__ int wsum[16];
    __shared__ int s_carry;
    int t = threadIdx.x, lane = t & 63, w = t >> 6;
    if (t == 0) s_carry = 0;
    __syncthreads();
    const int CHUNK = 8192;
    for (int base = 0; base < N_NODES; base += CHUNK) {
        int v[8];
        int idx0 = base + t * 8;
#pragma unroll
        for (int j = 0; j < 8; ++j) {
            int id = idx0 + j;
            v[j] = (id < N_NODES) ? deg[id] : 0;
        }
#pragma unroll
        for (int j = 1; j < 8; ++j) v[j] += v[j - 1];
        int tsum = v[7];
        int sc = tsum;
#pragma unroll
        for (int off = 1; off < 64; off <<= 1) {
            int u = __shfl_up(sc, off, 64);
            if (lane >= off) sc += u;
        }
        if (lane == 63) wsum[w] = sc;
        __syncthreads();
        int wpre = 0;
        for (int j = 0; j < w; ++j) wpre += wsum[j];
        int thread_excl = s_carry + wpre + (sc - tsum);
#pragma unroll
        for (int j = 0; j < 8; ++j) {
            int id = idx0 + j;
            if (id < N_NODES) rowstart[id] = thread_excl + (j ? v[j - 1] : 0);
        }
        __syncthreads();
        if (t == 1023) s_carry += wpre + sc;
        __syncthreads();
    }
    if (threadIdx.x == 0) rowstart[N_NODES] = s_carry;
}

// ---------------- scatter into both CSR orders + cross-position map ----------------
__global__ void k_scatter(const int* __restrict__ src, const int* __restrict__ dst,
                          const int* __restrict__ rows_d, const int* __restrict__ rows_s,
                          int* __restrict__ fill_d, int* __restrict__ fill_s,
                          int* __restrict__ srcs_d, int* __restrict__ dsts_s,
                          int* __restrict__ xq) {
    int e = blockIdx.x * blockDim.x + threadIdx.x;
    if (e >= N_EDGES) return;
    int s = src[e], d = dst[e];
    int p = rows_d[d] + atomicAdd(&fill_d[d], 1);
    int q = rows_s[s] + atomicAdd(&fill_s[s], 1);
    srcs_d[p] = s;
    dsts_s[q] = d;
    xq[p] = q;  // dst-order position -> src-order position of same edge
}

// ---------------- src-side segment softmax (wave per node, no atomics) ----------------
__global__ __launch_bounds__(256) void k_seg_src(const int* __restrict__ dsts_s,
                                                 const int* __restrict__ rows_s,
                                                 const float* __restrict__ el,
                                                 const float* __restrict__ er,
                                                 float* __restrict__ rs_arr) {
    int wid = threadIdx.x >> 6, lane = threadIdx.x & 63;
    int n = blockIdx.x * 4 + wid;
    if (n >= N_NODES) return;
    int rs = rows_s[n], re = rows_s[n + 1];
    if (rs >= re) return;
    float el0 = el[n * 3 + 0], el1 = el[n * 3 + 1], el2 = el[n * 3 + 2];
    bool single = (re - rs) <= 64;
    float m0 = -INFINITY, m1 = -INFINITY, m2 = -INFINITY;
    float c0 = 0, c1 = 0, c2 = 0;
    for (int p0 = rs; p0 < re; p0 += 64) {
        int p = p0 + lane;
        bool act = p < re;
        int d = act ? dsts_s[p] : 0;
        float t0 = act ? leaky(el0 + er[d * 3 + 0]) : -INFINITY;
        float t1 = act ? leaky(el1 + er[d * 3 + 1]) : -INFINITY;
        float t2 = act ? leaky(el2 + er[d * 3 + 2]) : -INFINITY;
        if (single) { c0 = t0; c1 = t1; c2 = t2; }
        m0 = fmaxf(m0, t0); m1 = fmaxf(m1, t1); m2 = fmaxf(m2, t2);
    }
#pragma unroll
    for (int off = 1; off < 64; off <<= 1) {
        m0 = fmaxf(m0, __shfl_xor(m0, off));
        m1 = fmaxf(m1, __shfl_xor(m1, off));
        m2 = fmaxf(m2, __shfl_xor(m2, off));
    }
    float s0 = 0, s1 = 0, s2 = 0;
    if (single) {
        bool act = (rs + lane) < re;
        c0 = act ? expf(c0 - m0) : 0.f;
        c1 = act ? expf(c1 - m1) : 0.f;
        c2 = act ? expf(c2 - m2) : 0.f;
        s0 = c0; s1 = c1; s2 = c2;
    } else {
        for (int p0 = rs; p0 < re; p0 += 64) {
            int p = p0 + lane;
            bool act = p < re;
            int d = act ? dsts_s[p] : 0;
            if (act) {
                s0 += expf(leaky(el0 + er[d * 3 + 0]) - m0);
                s1 += expf(leaky(el1 + er[d * 3 + 1]) - m1);
                s2 += expf(leaky(el2 + er[d * 3 + 2]) - m2);
            }
        }
    }
#pragma unroll
    for (int off = 1; off < 64; off <<= 1) {
        s0 += __shfl_xor(s0, off);
        s1 += __shfl_xor(s1, off);
        s2 += __shfl_xor(s2, off);
    }
    float i0 = 1.f / s0, i1 = 1.f / s1, i2 = 1.f / s2;
    if (single) {
        int p = rs + lane;
        if (p < re) {
            rs_arr[p * 3 + 0] = fmaxf(c0 * i0, EPS_V);
            rs_arr[p * 3 + 1] = fmaxf(c1 * i1, EPS_V);
            rs_arr[p * 3 + 2] = fmaxf(c2 * i2, EPS_V);
        }
    } else {
        for (int p0 = rs; p0 < re; p0 += 64) {
            int p = p0 + lane;
            if (p < re) {
                int d = dsts_s[p];
                rs_arr[p * 3 + 0] = fmaxf(expf(leaky(el0 + er[d * 3 + 0]) - m0) * i0, EPS_V);
                rs_arr[p * 3 + 1] = fmaxf(expf(leaky(el1 + er[d * 3 + 1]) - m1) * i1, EPS_V);
                rs_arr[p * 3 + 2] = fmaxf(expf(leaky(el2 + er[d * 3 + 2]) - m2) * i2, EPS_V);
            }
        }
    }
}

// -------- dst-side segment softmax + fused symmetric combine (wave per node) ----------
__global__ __launch_bounds__(256) void k_seg_dst_attn(const int* __restrict__ srcs_d,
                                                      const int* __restrict__ rows_d,
                                                      const float* __restrict__ el,
                                                      const float* __restrict__ er,
                                                      const int* __restrict__ xq,
                                                      const float* __restrict__ rs_arr,
                                                      float* __restrict__ a_sorted) {
    int wid = threadIdx.x >> 6, lane = threadIdx.x & 63;
    int n = blockIdx.x * 4 + wid;
    if (n >= N_NODES) return;
    int rs = rows_d[n], re = rows_d[n + 1];
    if (rs >= re) return;
    float er0 = er[n * 3 + 0], er1 = er[n * 3 + 1], er2 = er[n * 3 + 2];
    bool single = (re - rs) <= 64;
    float m0 = -INFINITY, m1 = -INFINITY, m2 = -INFINITY;
    float c0 = 0, c1 = 0, c2 = 0;
    for (int p0 = rs; p0 < re; p0 += 64) {
        int p = p0 + lane;
        bool act = p < re;
        int s = act ? srcs_d[p] : 0;
        float t0 = act ? leaky(el[s * 3 + 0] + er0) : -INFINITY;
        float t1 = act ? leaky(el[s * 3 + 1] + er1) : -INFINITY;
        float t2 = act ? leaky(el[s * 3 + 2] + er2) : -INFINITY;
        if (single) { c0 = t0; c1 = t1; c2 = t2; }
        m0 = fmaxf(m0, t0); m1 = fmaxf(m1, t1); m2 = fmaxf(m2, t2);
    }
#pragma unroll
    for (int off = 1; off < 64; off <<= 1) {
        m0 = fmaxf(m0, __shfl_xor(m0, off));
        m1 = fmaxf(m1, __shfl_xor(m1, off));
        m2 = fmaxf(m2, __shfl_xor(m2, off));
    }
    float s0 = 0, s1 = 0, s2 = 0;
    if (single) {
        bool act = (rs + lane) < re;
        c0 = act ? expf(c0 - m0) : 0.f;
        c1 = act ? expf(c1 - m1) : 0.f;
        c2 = act ? expf(c2 - m2) : 0.f;
        s0 = c0; s1 = c1; s2 = c2;
    } else {
        for (int p0 = rs; p0 < re; p0 += 64) {
            int p = p0 + lane;
            bool act = p < re;
            int s = act ? srcs_d[p] : 0;
            if (act) {
                s0 += expf(leaky(el[s * 3 + 0] + er0) - m0);
                s1 += expf(leaky(el[s * 3 + 1] + er1) - m1);
                s2 += expf(leaky(el[s * 3 + 2] + er2) - m2);
            }
        }
    }
#pragma unroll
    for (int off = 1; off < 64; off <<= 1) {
        s0 += __shfl_xor(s0, off);
        s1 += __shfl_xor(s1, off);
        s2 += __shfl_xor(s2, off);
    }
    float i0 = 1.f / s0, i1 = 1.f / s1, i2 = 1.f / s2;
    if (single) {
        int p = rs + lane;
        if (p < re) {
            int q = xq[p];
            a_sorted[p * 3 + 0] = sqrtf(fmaxf(c0 * i0, EPS_V) * rs_arr[q * 3 + 0]);
            a_sorted[p * 3 + 1] = sqrtf(fmaxf(c1 * i1, EPS_V) * rs_arr[q * 3 + 1]);
            a_sorted[p * 3 + 2] = sqrtf(fmaxf(c2 * i2, EPS_V) * rs_arr[q * 3 + 2]);
        }
    } else {
        for (int p0 = rs; p0 < re; p0 += 64) {
            int p = p0 + lane;
            if (p < re) {
                int s = srcs_d[p];
                int q = xq[p];
                float x0 = fmaxf(expf(leaky(el[s * 3 + 0] + er0) - m0) * i0, EPS_V);
                float x1 = fmaxf(expf(leaky(el[s * 3 + 1] + er1) - m1) * i1, EPS_V);
                float x2 = fmaxf(expf(leaky(el[s * 3 + 2] + er2) - m2) * i2, EPS_V);
                a_sorted[p * 3 + 0] = sqrtf(x0 * rs_arr[q * 3 + 0]);
                a_sorted[p * 3 + 1] = sqrtf(x1 * rs_arr[q * 3 + 1]);
                a_sorted[p * 3 + 2] = sqrtf(x2 * rs_arr[q * 3 + 2]);
            }
        }
    }
}

// ---------------- one diffusion hop ----------------
__global__ __launch_bounds__(256) void k_hop(const float* __restrict__ cur,
                                             const float* __restrict__ a_sorted,
                                             const int* __restrict__ rowstart,
                                             const int* __restrict__ src_sorted,
                                             float* __restrict__ out) {
    int wid = threadIdx.x >> 6, lane = threadIdx.x & 63;
    int n = blockIdx.x * 4 + wid;
    if (n >= N_NODES) return;
    if (lane >= HD) return;
    int h = lane >> 4;
    int rs = rowstart[n], re = rowstart[n + 1];
    float acc = 0.f;
    for (int p = rs; p < re; ++p) {
        int s = src_sorted[p];
        float a = a_sorted[p * HH + h];
        acc += a * cur[s * HD + lane];
    }
    out[n * HD + lane] = acc;
}

// ---------------- feat_trans + hop attention + output ----------------
__global__ void k_final(const float* __restrict__ ft, const float* __restrict__ cur1,
                        const float* __restrict__ cur2, const float* __restrict__ cur3,
                        const float* __restrict__ hop_l, const float* __restrict__ hop_r,
                        const float* __restrict__ pos_emb, const float* __restrict__ scales,
                        const float* __restrict__ offs, const float* __restrict__ bias,
                        float* __restrict__ out) {
    int i = blockIdx.x * blockDim.x + threadIdx.x;
    if (i >= N_NODES * HH) return;
    int h = i % HH;
    const float* rows[4] = {ft + (size_t)i * DD, cur1 + (size_t)i * DD,
                            cur2 + (size_t)i * DD, cur3 + (size_t)i * DD};
    float hk[4][DD];
#pragma unroll
    for (int k = 0; k < 4; ++k) {
        float x[DD];
        float m = 0.f;
#pragma unroll
        for (int d = 0; d < DD; ++d) {
            x[d] = rows[k][d];
            m += x[d];
        }
        m *= (1.f / DD);
        float v2 = 0.f;
#pragma unroll
        for (int d = 0; d < DD; ++d) {
            float c = x[d] - m;
            v2 += c * c;
        }
        v2 = v2 * (1.f / DD) + EPS_V;
        float rsq = rsqrtf(v2);
#pragma unroll
        for (int d = 0; d < DD; ++d) {
            hk[k][d] = (x[d] - m) * scales[k * HD + h * DD + d] * rsq +
                       offs[k * HD + h * DD + d] + pos_emb[h * 64 + k * DD + d];
        }
    }
    float al = 0.f;
#pragma unroll
    for (int d = 0; d < DD; ++d) al += hk[0][d] * hop_l[h * DD + d];
    float ar[3], mx = -1e30f;
#pragma unroll
    for (int k = 0; k < 3; ++k) {
        float s = 0.f;
#pragma unroll
        for (int d = 0; d < DD; ++d) s += hk[k + 1][d] * hop_r[h * DD + d];
        ar[k] = leaky(s + al);
        mx = fmaxf(mx, ar[k]);
    }
    float den = 0.f, wgt[3];
#pragma unroll
    for (int k = 0; k < 3; ++k) {
        wgt[k] = expf(ar[k] - mx);
        den += wgt[k];
    }
#pragma unroll
    for (int k = 0; k < 3; ++k) wgt[k] /= den;
#pragma unroll
    for (int d = 0; d < DD; ++d) {
        float o = hk[1][d] * wgt[0] + hk[2][d] * wgt[1] + hk[3][d] * wgt[2] +
                  bias[h * DD + d];
        out[i * DD + d] = o;
    }
}

// ---------------- workspace layout (float-element offsets) ----------------
// overlays (safe by stream order):
//   rs_arr  aliases CUR1 (written k_seg_src, read k_seg_dst_attn, both before hop1)
//   dsts_s  aliases CUR2 (read k_seg_src, before hop2 writes cur2)
//   xq      aliases CUR3 (read k_seg_dst_attn, before hop3 writes cur3)
#define OFF_FT     0u          // 4.8M
#define OFF_EL     4800000u    // 300k
#define OFF_ER     5100000u    // 300k
#define OFF_DEGD   5400000u    // 100k  -- zero region start
#define OFF_FILLD  5500000u    // 100k
#define OFF_DEGS   5600000u    // 100k
#define OFF_FILLS  5700000u    // 100k  -- zero region end (5.8M)
#define OFF_ROWD   5800000u    // 100001
#define OFF_ROWS_  5900008u    // 100001
#define OFF_SRCSD  6000016u    // 1.6M
#define OFF_ASORT  7600016u    // 4.8M
#define OFF_CUR1   12400016u   // 4.8M (alias rs_arr)
#define OFF_CUR2   17200016u   // 4.8M (alias dsts_s)
#define OFF_CUR3   22000016u   // 4.8M (alias xq)
#define WS_FLOATS  26800016u   // 107.2 MB

extern "C" void kernel_launch(void* const* d_in, const int* in_sizes, int n_in,
                              void* d_out, int out_size, void* d_ws, size_t ws_size,
                              hipStream_t stream) {
    if (ws_size < (size_t)WS_FLOATS * 4) return;

    const float* feat   = (const float*)d_in[0];
    const int*   src    = (const int*)d_in[1];
    const int*   dst    = (const int*)d_in[2];
    const float* fc_W   = (const float*)d_in[3];
    const float* attn_l = (const float*)d_in[4];
    const float* attn_r = (const float*)d_in[5];
    const float* hop_l  = (const float*)d_in[6];
    const float* hop_r  = (const float*)d_in[7];
    const float* pos    = (const float*)d_in[8];
    const float* scal   = (const float*)d_in[9];
    const float* offs   = (const float*)d_in[10];
    const float* bias   = (const float*)d_in[11];
    float* out = (float*)d_out;

    float* ws = (float*)d_ws;
    float* ft       = ws + OFF_FT;
    float* el       = ws + OFF_EL;
    float* er       = ws + OFF_ER;
    int*   deg_d    = (int*)(ws + OFF_DEGD);
    int*   fill_d   = (int*)(ws + OFF_FILLD);
    int*   deg_s    = (int*)(ws + OFF_DEGS);
    int*   fill_s   = (int*)(ws + OFF_FILLS);
    int*   rows_d   = (int*)(ws + OFF_ROWD);
    int*   rows_s   = (int*)(ws + OFF_ROWS_);
    int*   srcs_d   = (int*)(ws + OFF_SRCSD);
    float* a_sorted = ws + OFF_ASORT;
    float* cur1     = ws + OFF_CUR1;
    float* cur2     = ws + OFF_CUR2;
    float* cur3     = ws + OFF_CUR3;
    float* rs_arr   = cur1;            // overlay
    int*   dsts_s   = (int*)cur2;      // overlay
    int*   xq       = (int*)cur3;      // overlay

    hipMemsetAsync(ws + OFF_DEGD, 0, (size_t)(OFF_ROWD - OFF_DEGD) * 4, stream);

    k_gemm<<<(N_NODES + GR - 1) / GR, 256, 0, stream>>>(feat, fc_W, ft);
    k_eler<<<(N_NODES * HH + 255) / 256, 256, 0, stream>>>(ft, attn_l, attn_r, el, er);
    k_hist<<<(N_EDGES + 255) / 256, 256, 0, stream>>>(src, dst, deg_s, deg_d);
    k_scan2<<<2, 1024, 0, stream>>>(deg_d, rows_d, deg_s, rows_s);
    k_scatter<<<(N_EDGES + 255) / 256, 256, 0, stream>>>(src, dst, rows_d, rows_s,
                                                         fill_d, fill_s, srcs_d, dsts_s, xq);
    k_seg_src<<<(N_NODES + 3) / 4, 256, 0, stream>>>(dsts_s, rows_s, el, er, rs_arr);
    k_seg_dst_attn<<<(N_NODES + 3) / 4, 256, 0, stream>>>(srcs_d, rows_d, el, er, xq,
                                                          rs_arr, a_sorted);
    k_hop<<<(N_NODES + 3) / 4, 256, 0, stream>>>(ft, a_sorted, rows_d, srcs_d, cur1);
    k_hop<<<(N_NODES + 3) / 4, 256, 0, stream>>>(cur1, a_sorted, rows_d, srcs_d, cur2);
    k_hop<<<(N_NODES + 3) / 4, 256, 0, stream>>>(cur2, a_sorted, rows_d, srcs_d, cur3);
    k_final<<<(N_NODES * HH + 255) / 256, 256, 0, stream>>>(ft, cur1, cur2, cur3, hop_l,
                                                            hop_r, pos, scal, offs, bias,
                                                            out);
}

// Round 4
// 1057.263 us; speedup vs baseline: 1.6418x; 1.0739x over previous
//
#include <hip/hip_runtime.h>
#include <hip/hip_bf16.h>

typedef __hip_bfloat16 bf16;

#define N_NODES 100000
#define N_EDGES 1600000
#define IN_F    128
#define HH      3      // heads
#define DD      16     // out feats per head
#define HD      48     // HH*DD
#define NEG_SLOPE 0.2f
#define EPS_V   1e-9f

__device__ __forceinline__ float leaky(float x) { return x >= 0.f ? x : NEG_SLOPE * x; }
__device__ __forceinline__ float b2f(bf16 x) { return __bfloat162float(x); }

// ---------------- GEMM: ft[N,48] = feat[N,128] @ W[128,48]; also emits bf16 copy -------
#define GR 32
__global__ __launch_bounds__(256) void k_gemm(const float* __restrict__ feat,
                                              const float* __restrict__ W,
                                              float* __restrict__ ft,
                                              bf16* __restrict__ ft16) {
    __shared__ float Ws[IN_F][HD];        // 24 KB
    __shared__ float Fs[GR][IN_F + 1];
    int t = threadIdx.x;
    for (int i = t; i < IN_F * HD; i += 256) Ws[i / HD][i % HD] = W[i];
    int row0 = blockIdx.x * GR;
    for (int i = t; i < GR * IN_F; i += 256) {
        int r = i >> 7, c = i & 127;
        int gr = row0 + r;
        Fs[r][c] = (gr < N_NODES) ? feat[gr * IN_F + c] : 0.f;
    }
    __syncthreads();
    int r = t >> 3, cg = t & 7;
    float acc[6] = {0, 0, 0, 0, 0, 0};
    for (int k = 0; k < IN_F; ++k) {
        float a = Fs[r][k];
#pragma unroll
        for (int j = 0; j < 6; ++j) acc[j] += a * Ws[k][cg * 6 + j];
    }
    int gr = row0 + r;
    if (gr < N_NODES) {
#pragma unroll
        for (int j = 0; j < 6; ++j) {
            ft[gr * HD + cg * 6 + j] = acc[j];
            ft16[gr * HD + cg * 6 + j] = __float2bfloat16(acc[j]);
        }
    }
}

// ---------------- el/er ----------------
__global__ void k_eler(const float* __restrict__ ft, const float* __restrict__ attn_l,
                       const float* __restrict__ attn_r, float* __restrict__ el,
                       float* __restrict__ er) {
    int i = blockIdx.x * blockDim.x + threadIdx.x;
    if (i >= N_NODES * HH) return;
    int h = i % HH;
    float sl = 0.f, sr = 0.f;
#pragma unroll
    for (int d = 0; d < DD; ++d) {
        float v = ft[i * DD + d];
        sl += v * attn_l[h * DD + d];
        sr += v * attn_r[h * DD + d];
    }
    el[i] = sl;
    er[i] = sr;
}

// ---------------- degree histograms (both directions) ----------------
__global__ void k_hist(const int* __restrict__ src, const int* __restrict__ dst,
                       int* __restrict__ deg_s, int* __restrict__ deg_d) {
    int e = blockIdx.x * blockDim.x + threadIdx.x;
    if (e < N_EDGES) {
        atomicAdd(&deg_d[dst[e]], 1);
        atomicAdd(&deg_s[src[e]], 1);
    }
}

// ---------------- exclusive scan; block 0: dst-deg, block 1: src-deg ----------------
__global__ __launch_bounds__(1024) void k_scan2(const int* __restrict__ deg_d,
                                                int* __restrict__ rows_d,
                                                const int* __restrict__ deg_s,
                                                int* __restrict__ rows_s) {
    const int* deg = blockIdx.x ? deg_s : deg_d;
    int* rowstart = blockIdx.x ? rows_s : rows_d;
    __shared__ int wsum[16];
    __shared__ int s_carry;
    int t = threadIdx.x, lane = t & 63, w = t >> 6;
    if (t == 0) s_carry = 0;
    __syncthreads();
    const int CHUNK = 8192;
    for (int base = 0; base < N_NODES; base += CHUNK) {
        int v[8];
        int idx0 = base + t * 8;
#pragma unroll
        for (int j = 0; j < 8; ++j) {
            int id = idx0 + j;
            v[j] = (id < N_NODES) ? deg[id] : 0;
        }
#pragma unroll
        for (int j = 1; j < 8; ++j) v[j] += v[j - 1];
        int tsum = v[7];
        int sc = tsum;
#pragma unroll
        for (int off = 1; off < 64; off <<= 1) {
            int u = __shfl_up(sc, off, 64);
            if (lane >= off) sc += u;
        }
        if (lane == 63) wsum[w] = sc;
        __syncthreads();
        int wpre = 0;
        for (int j = 0; j < w; ++j) wpre += wsum[j];
        int thread_excl = s_carry + wpre + (sc - tsum);
#pragma unroll
        for (int j = 0; j < 8; ++j) {
            int id = idx0 + j;
            if (id < N_NODES) rowstart[id] = thread_excl + (j ? v[j - 1] : 0);
        }
        __syncthreads();
        if (t == 1023) s_carry += wpre + sc;
        __syncthreads();
    }
    if (threadIdx.x == 0) rowstart[N_NODES] = s_carry;
}

// ---------------- scatter into both CSR orders (2 scattered stores/edge) ---------------
__global__ void k_scatter(const int* __restrict__ src, const int* __restrict__ dst,
                          const int* __restrict__ rows_d, const int* __restrict__ rows_s,
                          int* __restrict__ fill_d, int* __restrict__ fill_s,
                          int* __restrict__ srcs_d, int* __restrict__ dsts_s) {
    int e = blockIdx.x * blockDim.x + threadIdx.x;
    if (e >= N_EDGES) return;
    int s = src[e], d = dst[e];
    int p = rows_d[d] + atomicAdd(&fill_d[d], 1);
    int q = rows_s[s] + atomicAdd(&fill_s[s], 1);
    srcs_d[p] = s;
    dsts_s[q] = d;
}

// -------- src-side segment softmax stats: per-node (max, sum) only ----------
__global__ __launch_bounds__(256) void k_seg_src(const int* __restrict__ dsts_s,
                                                 const int* __restrict__ rows_s,
                                                 const float* __restrict__ el,
                                                 const float* __restrict__ er,
                                                 float2* __restrict__ mssrc) {
    int wid = threadIdx.x >> 6, lane = threadIdx.x & 63;
    int n = blockIdx.x * 4 + wid;
    if (n >= N_NODES) return;
    int rs = rows_s[n], re = rows_s[n + 1];
    if (rs >= re) return;
    float el0 = el[n * 3 + 0], el1 = el[n * 3 + 1], el2 = el[n * 3 + 2];
    bool single = (re - rs) <= 64;
    float m0 = -INFINITY, m1 = -INFINITY, m2 = -INFINITY;
    float c0 = -INFINITY, c1 = -INFINITY, c2 = -INFINITY;  // cached raw scores
    for (int p0 = rs; p0 < re; p0 += 64) {
        int p = p0 + lane;
        bool act = p < re;
        int d = act ? dsts_s[p] : 0;
        float t0 = act ? leaky(el0 + er[d * 3 + 0]) : -INFINITY;
        float t1 = act ? leaky(el1 + er[d * 3 + 1]) : -INFINITY;
        float t2 = act ? leaky(el2 + er[d * 3 + 2]) : -INFINITY;
        if (single) { c0 = t0; c1 = t1; c2 = t2; }
        m0 = fmaxf(m0, t0); m1 = fmaxf(m1, t1); m2 = fmaxf(m2, t2);
    }
#pragma unroll
    for (int off = 1; off < 64; off <<= 1) {
        m0 = fmaxf(m0, __shfl_xor(m0, off));
        m1 = fmaxf(m1, __shfl_xor(m1, off));
        m2 = fmaxf(m2, __shfl_xor(m2, off));
    }
    float s0 = 0, s1 = 0, s2 = 0;
    if (single) {
        bool act = (rs + lane) < re;
        s0 = act ? expf(c0 - m0) : 0.f;
        s1 = act ? expf(c1 - m1) : 0.f;
        s2 = act ? expf(c2 - m2) : 0.f;
    } else {
        for (int p0 = rs; p0 < re; p0 += 64) {
            int p = p0 + lane;
            if (p < re) {
                int d = dsts_s[p];
                s0 += expf(leaky(el0 + er[d * 3 + 0]) - m0);
                s1 += expf(leaky(el1 + er[d * 3 + 1]) - m1);
                s2 += expf(leaky(el2 + er[d * 3 + 2]) - m2);
            }
        }
    }
#pragma unroll
    for (int off = 1; off < 64; off <<= 1) {
        s0 += __shfl_xor(s0, off);
        s1 += __shfl_xor(s1, off);
        s2 += __shfl_xor(s2, off);
    }
    if (lane == 0) {
        mssrc[n * 3 + 0] = make_float2(m0, s0);
        mssrc[n * 3 + 1] = make_float2(m1, s1);
        mssrc[n * 3 + 2] = make_float2(m2, s2);
    }
}

// -------- dst-side stats + fused symmetric attention coefficient ----------
__global__ __launch_bounds__(256) void k_seg_dst_attn(const int* __restrict__ srcs_d,
                                                      const int* __restrict__ rows_d,
                                                      const float* __restrict__ el,
                                                      const float* __restrict__ er,
                                                      const float2* __restrict__ mssrc,
                                                      float* __restrict__ a_sorted) {
    int wid = threadIdx.x >> 6, lane = threadIdx.x & 63;
    int n = blockIdx.x * 4 + wid;
    if (n >= N_NODES) return;
    int rs = rows_d[n], re = rows_d[n + 1];
    if (rs >= re) return;
    float er0 = er[n * 3 + 0], er1 = er[n * 3 + 1], er2 = er[n * 3 + 2];
    bool single = (re - rs) <= 64;
    float m0 = -INFINITY, m1 = -INFINITY, m2 = -INFINITY;
    float c0 = -INFINITY, c1 = -INFINITY, c2 = -INFINITY;
    int scache = 0;
    for (int p0 = rs; p0 < re; p0 += 64) {
        int p = p0 + lane;
        bool act = p < re;
        int s = act ? srcs_d[p] : 0;
        if (single) scache = s;
        float t0 = act ? leaky(el[s * 3 + 0] + er0) : -INFINITY;
        float t1 = act ? leaky(el[s * 3 + 1] + er1) : -INFINITY;
        float t2 = act ? leaky(el[s * 3 + 2] + er2) : -INFINITY;
        if (single) { c0 = t0; c1 = t1; c2 = t2; }
        m0 = fmaxf(m0, t0); m1 = fmaxf(m1, t1); m2 = fmaxf(m2, t2);
    }
#pragma unroll
    for (int off = 1; off < 64; off <<= 1) {
        m0 = fmaxf(m0, __shfl_xor(m0, off));
        m1 = fmaxf(m1, __shfl_xor(m1, off));
        m2 = fmaxf(m2, __shfl_xor(m2, off));
    }
    float s0 = 0, s1 = 0, s2 = 0;
    if (single) {
        bool act = (rs + lane) < re;
        s0 = act ? expf(c0 - m0) : 0.f;
        s1 = act ? expf(c1 - m1) : 0.f;
        s2 = act ? expf(c2 - m2) : 0.f;
    } else {
        for (int p0 = rs; p0 < re; p0 += 64) {
            int p = p0 + lane;
            if (p < re) {
                int s = srcs_d[p];
                s0 += expf(leaky(el[s * 3 + 0] + er0) - m0);
                s1 += expf(leaky(el[s * 3 + 1] + er1) - m1);
                s2 += expf(leaky(el[s * 3 + 2] + er2) - m2);
            }
        }
    }
#pragma unroll
    for (int off = 1; off < 64; off <<= 1) {
        s0 += __shfl_xor(s0, off);
        s1 += __shfl_xor(s1, off);
        s2 += __shfl_xor(s2, off);
    }
    float i0 = 1.f / s0, i1 = 1.f / s1, i2 = 1.f / s2;
    for (int p0 = rs; p0 < re; p0 += 64) {
        int p = p0 + lane;
        if (p >= re) break;
        int s = single ? scache : srcs_d[p];
        float t0, t1, t2;
        if (single) { t0 = c0; t1 = c1; t2 = c2; }
        else {
            t0 = leaky(el[s * 3 + 0] + er0);
            t1 = leaky(el[s * 3 + 1] + er1);
            t2 = leaky(el[s * 3 + 2] + er2);
        }
        float2 a0 = mssrc[s * 3 + 0], a1 = mssrc[s * 3 + 1], a2 = mssrc[s * 3 + 2];
        float d0 = fmaxf(expf(t0 - m0) * i0, EPS_V);
        float d1 = fmaxf(expf(t1 - m1) * i1, EPS_V);
        float d2 = fmaxf(expf(t2 - m2) * i2, EPS_V);
        float u0 = fmaxf(expf(t0 - a0.x) / a0.y, EPS_V);
        float u1 = fmaxf(expf(t1 - a1.x) / a1.y, EPS_V);
        float u2 = fmaxf(expf(t2 - a2.x) / a2.y, EPS_V);
        a_sorted[p * 3 + 0] = sqrtf(d0 * u0);
        a_sorted[p * 3 + 1] = sqrtf(d1 * u1);
        a_sorted[p * 3 + 2] = sqrtf(d2 * u2);
    }
}

// ---------------- one diffusion hop (bf16 features, f32 accumulate) ----------------
__global__ __launch_bounds__(256) void k_hop(const bf16* __restrict__ cur,
                                             const float* __restrict__ a_sorted,
                                             const int* __restrict__ rowstart,
                                             const int* __restrict__ src_sorted,
                                             bf16* __restrict__ out) {
    int wid = threadIdx.x >> 6, lane = threadIdx.x & 63;
    int n = blockIdx.x * 4 + wid;
    if (n >= N_NODES) return;
    if (lane >= HD) return;
    int h = lane >> 4;
    int rs = rowstart[n], re = rowstart[n + 1];
    float acc = 0.f;
    for (int p = rs; p < re; ++p) {
        int s = src_sorted[p];
        float a = a_sorted[p * HH + h];
        acc += a * b2f(cur[s * HD + lane]);
    }
    out[n * HD + lane] = __float2bfloat16(acc);
}

// ---------------- feat_trans + hop attention + output ----------------
__global__ void k_final(const float* __restrict__ ft, const bf16* __restrict__ cur1,
                        const bf16* __restrict__ cur2, const bf16* __restrict__ cur3,
                        const float* __restrict__ hop_l, const float* __restrict__ hop_r,
                        const float* __restrict__ pos_emb, const float* __restrict__ scales,
                        const float* __restrict__ offs, const float* __restrict__ bias,
                        float* __restrict__ out) {
    int i = blockIdx.x * blockDim.x + threadIdx.x;
    if (i >= N_NODES * HH) return;
    int h = i % HH;
    float hk[4][DD];
#pragma unroll
    for (int k = 0; k < 4; ++k) {
        float x[DD];
#pragma unroll
        for (int d = 0; d < DD; ++d) {
            x[d] = (k == 0) ? ft[(size_t)i * DD + d]
                 : (k == 1) ? b2f(cur1[(size_t)i * DD + d])
                 : (k == 2) ? b2f(cur2[(size_t)i * DD + d])
                            : b2f(cur3[(size_t)i * DD + d]);
        }
        float m = 0.f;
#pragma unroll
        for (int d = 0; d < DD; ++d) m += x[d];
        m *= (1.f / DD);
        float v2 = 0.f;
#pragma unroll
        for (int d = 0; d < DD; ++d) {
            float c = x[d] - m;
            v2 += c * c;
        }
        v2 = v2 * (1.f / DD) + EPS_V;
        float rsq = rsqrtf(v2);
#pragma unroll
        for (int d = 0; d < DD; ++d) {
            hk[k][d] = (x[d] - m) * scales[k * HD + h * DD + d] * rsq +
                       offs[k * HD + h * DD + d] + pos_emb[h * 64 + k * DD + d];
        }
    }
    float al = 0.f;
#pragma unroll
    for (int d = 0; d < DD; ++d) al += hk[0][d] * hop_l[h * DD + d];
    float ar[3], mx = -1e30f;
#pragma unroll
    for (int k = 0; k < 3; ++k) {
        float s = 0.f;
#pragma unroll
        for (int d = 0; d < DD; ++d) s += hk[k + 1][d] * hop_r[h * DD + d];
        ar[k] = leaky(s + al);
        mx = fmaxf(mx, ar[k]);
    }
    float den = 0.f, wgt[3];
#pragma unroll
    for (int k = 0; k < 3; ++k) {
        wgt[k] = expf(ar[k] - mx);
        den += wgt[k];
    }
#pragma unroll
    for (int k = 0; k < 3; ++k) wgt[k] /= den;
#pragma unroll
    for (int d = 0; d < DD; ++d) {
        float o = hk[1][d] * wgt[0] + hk[2][d] * wgt[1] + hk[3][d] * wgt[2] +
                  bias[h * DD + d];
        out[i * DD + d] = o;
    }
}

// ---------------- workspace layout (float-element offsets) ----------------
#define OFF_FT     0u          // 4.8M f32
#define OFF_FT16   4800000u    // 4.8M bf16 = 2.4M slots
#define OFF_EL     7200000u    // 300k
#define OFF_ER     7500000u    // 300k
#define OFF_MSSRC  7800000u    // 300k float2 = 600k slots
#define OFF_DEGD   8400000u    // 100k  -- zero region start
#define OFF_FILLD  8500000u
#define OFF_DEGS   8600000u
#define OFF_FILLS  8700000u    //       -- zero region end (8.8M)
#define OFF_ROWD   8800000u    // 100001
#define OFF_ROWS_  8900008u    // 100001
#define OFF_SRCSD  9000016u    // 1.6M
#define OFF_DSTSS  10600016u   // 1.6M
#define OFF_ASORT  12200016u   // 4.8M
#define OFF_CUR1   17000016u   // 4.8M bf16 = 2.4M slots
#define OFF_CUR2   19400016u
#define OFF_CUR3   21800016u
#define WS_FLOATS  24200016u   // 96.8 MB

extern "C" void kernel_launch(void* const* d_in, const int* in_sizes, int n_in,
                              void* d_out, int out_size, void* d_ws, size_t ws_size,
                              hipStream_t stream) {
    if (ws_size < (size_t)WS_FLOATS * 4) return;

    const float* feat   = (const float*)d_in[0];
    const int*   src    = (const int*)d_in[1];
    const int*   dst    = (const int*)d_in[2];
    const float* fc_W   = (const float*)d_in[3];
    const float* attn_l = (const float*)d_in[4];
    const float* attn_r = (const float*)d_in[5];
    const float* hop_l  = (const float*)d_in[6];
    const float* hop_r  = (const float*)d_in[7];
    const float* pos    = (const float*)d_in[8];
    const float* scal   = (const float*)d_in[9];
    const float* offs   = (const float*)d_in[10];
    const float* bias   = (const float*)d_in[11];
    float* out = (float*)d_out;

    float* ws = (float*)d_ws;
    float*  ft      = ws + OFF_FT;
    bf16*   ft16    = (bf16*)(ws + OFF_FT16);
    float*  el      = ws + OFF_EL;
    float*  er      = ws + OFF_ER;
    float2* mssrc   = (float2*)(ws + OFF_MSSRC);
    int*    deg_d   = (int*)(ws + OFF_DEGD);
    int*    fill_d  = (int*)(ws + OFF_FILLD);
    int*    deg_s   = (int*)(ws + OFF_DEGS);
    int*    fill_s  = (int*)(ws + OFF_FILLS);
    int*    rows_d  = (int*)(ws + OFF_ROWD);
    int*    rows_s  = (int*)(ws + OFF_ROWS_);
    int*    srcs_d  = (int*)(ws + OFF_SRCSD);
    int*    dsts_s  = (int*)(ws + OFF_DSTSS);
    float*  a_sorted= ws + OFF_ASORT;
    bf16*   cur1    = (bf16*)(ws + OFF_CUR1);
    bf16*   cur2    = (bf16*)(ws + OFF_CUR2);
    bf16*   cur3    = (bf16*)(ws + OFF_CUR3);

    hipMemsetAsync(ws + OFF_DEGD, 0, (size_t)(OFF_ROWD - OFF_DEGD) * 4, stream);

    k_gemm<<<(N_NODES + GR - 1) / GR, 256, 0, stream>>>(feat, fc_W, ft, ft16);
    k_eler<<<(N_NODES * HH + 255) / 256, 256, 0, stream>>>(ft, attn_l, attn_r, el, er);
    k_hist<<<(N_EDGES + 255) / 256, 256, 0, stream>>>(src, dst, deg_s, deg_d);
    k_scan2<<<2, 1024, 0, stream>>>(deg_d, rows_d, deg_s, rows_s);
    k_scatter<<<(N_EDGES + 255) / 256, 256, 0, stream>>>(src, dst, rows_d, rows_s,
                                                         fill_d, fill_s, srcs_d, dsts_s);
    k_seg_src<<<(N_NODES + 3) / 4, 256, 0, stream>>>(dsts_s, rows_s, el, er, mssrc);
    k_seg_dst_attn<<<(N_NODES + 3) / 4, 256, 0, stream>>>(srcs_d, rows_d, el, er,
                                                          mssrc, a_sorted);
    k_hop<<<(N_NODES + 3) / 4, 256, 0, stream>>>(ft16, a_sorted, rows_d, srcs_d, cur1);
    k_hop<<<(N_NODES + 3) / 4, 256, 0, stream>>>(cur1, a_sorted, rows_d, srcs_d, cur2);
    k_hop<<<(N_NODES + 3) / 4, 256, 0, stream>>>(cur2, a_sorted, rows_d, srcs_d, cur3);
    k_final<<<(N_NODES * HH + 255) / 256, 256, 0, stream>>>(ft, cur1, cur2, cur3, hop_l,
                                                            hop_r, pos, scal, offs, bias,
                                                            out);
}

// Round 5
// 765.244 us; speedup vs baseline: 2.2684x; 1.3816x over previous
//
#include <hip/hip_runtime.h>
#include <hip/hip_bf16.h>

typedef __hip_bfloat16 bf16;

#define N_NODES 100000
#define N_EDGES 1600000
#define IN_F    128
#define HH      3      // heads
#define DD      16     // out feats per head
#define HD      48     // HH*DD
#define NEG_SLOPE 0.2f
#define EPS_V   1e-9f

#define NB      391    // ceil(N_NODES / 256) buckets
#define BW_SH   8      // bucket = node >> 8 (256 nodes per bucket)
#define MS_T    8192   // edges per multisplit workgroup

__device__ __forceinline__ float leaky(float x) { return x >= 0.f ? x : NEG_SLOPE * x; }
__device__ __forceinline__ float b2f(bf16 x) { return __bfloat162float(x); }

// ---------------- GEMM: ft[N,48] = feat[N,128] @ W[128,48]; also emits bf16 copy -------
#define GR 32
__global__ __launch_bounds__(256) void k_gemm(const float* __restrict__ feat,
                                              const float* __restrict__ W,
                                              float* __restrict__ ft,
                                              bf16* __restrict__ ft16) {
    __shared__ float Ws[IN_F][HD];
    __shared__ float Fs[GR][IN_F + 1];
    int t = threadIdx.x;
    for (int i = t; i < IN_F * HD; i += 256) Ws[i / HD][i % HD] = W[i];
    int row0 = blockIdx.x * GR;
    for (int i = t; i < GR * IN_F; i += 256) {
        int r = i >> 7, c = i & 127;
        int gr = row0 + r;
        Fs[r][c] = (gr < N_NODES) ? feat[gr * IN_F + c] : 0.f;
    }
    __syncthreads();
    int r = t >> 3, cg = t & 7;
    float acc[6] = {0, 0, 0, 0, 0, 0};
    for (int k = 0; k < IN_F; ++k) {
        float a = Fs[r][k];
#pragma unroll
        for (int j = 0; j < 6; ++j) acc[j] += a * Ws[k][cg * 6 + j];
    }
    int gr = row0 + r;
    if (gr < N_NODES) {
#pragma unroll
        for (int j = 0; j < 6; ++j) {
            ft[gr * HD + cg * 6 + j] = acc[j];
            ft16[gr * HD + cg * 6 + j] = __float2bfloat16(acc[j]);
        }
    }
}

// ---------------- el/er ----------------
__global__ void k_eler(const float* __restrict__ ft, const float* __restrict__ attn_l,
                       const float* __restrict__ attn_r, float* __restrict__ el,
                       float* __restrict__ er) {
    int i = blockIdx.x * blockDim.x + threadIdx.x;
    if (i >= N_NODES * HH) return;
    int h = i % HH;
    float sl = 0.f, sr = 0.f;
#pragma unroll
    for (int d = 0; d < DD; ++d) {
        float v = ft[i * DD + d];
        sl += v * attn_l[h * DD + d];
        sr += v * attn_r[h * DD + d];
    }
    el[i] = sl;
    er[i] = sr;
}

// ---------------- K1: per-bucket histograms (LDS-privatized) ----------------
__global__ __launch_bounds__(256) void k_bhist(const int* __restrict__ src,
                                               const int* __restrict__ dst,
                                               int* __restrict__ bcnt_s,
                                               int* __restrict__ bcnt_d) {
    __shared__ int ls[NB], ld_[NB];
    int t = threadIdx.x;
    for (int i = t; i < NB; i += 256) { ls[i] = 0; ld_[i] = 0; }
    __syncthreads();
    for (int e = blockIdx.x * 256 + t; e < N_EDGES; e += gridDim.x * 256) {
        atomicAdd(&ld_[dst[e] >> BW_SH], 1);
        atomicAdd(&ls[src[e] >> BW_SH], 1);
    }
    __syncthreads();
    for (int i = t; i < NB; i += 256) {
        if (ld_[i]) atomicAdd(&bcnt_d[i], ld_[i]);
        if (ls[i]) atomicAdd(&bcnt_s[i], ls[i]);
    }
}

// ---------------- K2: scan bucket counts -> bucket bases (+ sentinels) -------------
__global__ __launch_bounds__(512) void k_bscan(const int* __restrict__ bcnt_d,
                                               int* __restrict__ bbase_d,
                                               const int* __restrict__ bcnt_s,
                                               int* __restrict__ bbase_s,
                                               int* __restrict__ rows_d,
                                               int* __restrict__ rows_s) {
    __shared__ int buf[512];
    const int* c = blockIdx.x ? bcnt_s : bcnt_d;
    int* o = blockIdx.x ? bbase_s : bbase_d;
    int t = threadIdx.x;
    int v = (t < NB) ? c[t] : 0;
    buf[t] = v;
    __syncthreads();
    for (int off = 1; off < 512; off <<= 1) {
        int u = (t >= off) ? buf[t - off] : 0;
        __syncthreads();
        buf[t] += u;
        __syncthreads();
    }
    if (t < NB) o[t] = buf[t] - v;      // exclusive
    if (t == NB - 1) o[NB] = buf[t];    // == N_EDGES
    if (t == 0) {
        if (blockIdx.x) rows_s[N_NODES] = N_EDGES;
        else            rows_d[N_NODES] = N_EDGES;
    }
}

// ---------------- K3: multisplit — bucket edges for both directions ----------------
// bkt_d entry: s | ((d & 255) << 17)   (bucketed by d)
// bkt_s entry: d | ((s & 255) << 17)   (bucketed by s)
__global__ __launch_bounds__(256) void k_msplit(const int* __restrict__ src,
                                                const int* __restrict__ dst,
                                                const int* __restrict__ bbase_d,
                                                const int* __restrict__ bbase_s,
                                                int* __restrict__ bfill_d,
                                                int* __restrict__ bfill_s,
                                                unsigned* __restrict__ bkt_d,
                                                unsigned* __restrict__ bkt_s) {
    __shared__ int lcD[NB], lcS[NB], wbD[NB], wbS[NB], rkD[NB], rkS[NB];
    int t = threadIdx.x;
    int e0 = blockIdx.x * MS_T;
    int e1 = min(e0 + MS_T, N_EDGES);
    for (int i = t; i < NB; i += 256) { lcD[i] = 0; lcS[i] = 0; rkD[i] = 0; rkS[i] = 0; }
    __syncthreads();
    for (int e = e0 + t; e < e1; e += 256) {
        atomicAdd(&lcD[dst[e] >> BW_SH], 1);
        atomicAdd(&lcS[src[e] >> BW_SH], 1);
    }
    __syncthreads();
    for (int i = t; i < NB; i += 256) {
        wbD[i] = bbase_d[i] + (lcD[i] ? atomicAdd(&bfill_d[i], lcD[i]) : 0);
        wbS[i] = bbase_s[i] + (lcS[i] ? atomicAdd(&bfill_s[i], lcS[i]) : 0);
    }
    __syncthreads();
    for (int e = e0 + t; e < e1; e += 256) {
        int s = src[e], d = dst[e];
        int bd = d >> BW_SH, bs = s >> BW_SH;
        int rd = atomicAdd(&rkD[bd], 1);
        int rs = atomicAdd(&rkS[bs], 1);
        bkt_d[wbD[bd] + rd] = (unsigned)s | ((unsigned)(d & 255) << 17);
        bkt_s[wbS[bs] + rs] = (unsigned)d | ((unsigned)(s & 255) << 17);
    }
}

// ---------------- K4: per-bucket CSR finalize (rows + payload scatter) --------------
__global__ __launch_bounds__(256) void k_bfinal(const unsigned* __restrict__ bkt,
                                                const int* __restrict__ bbase,
                                                int* __restrict__ rows,
                                                int* __restrict__ outarr) {
    __shared__ int cnt[256], pre[256], rnk[256], wsum[4];
    int b = blockIdx.x, t = threadIdx.x;
    int base = bbase[b], end = bbase[b + 1];
    cnt[t] = 0; rnk[t] = 0;
    __syncthreads();
    for (int i = base + t; i < end; i += 256)
        atomicAdd(&cnt[(bkt[i] >> 17) & 255], 1);
    __syncthreads();
    int lane = t & 63, w = t >> 6;
    int v = cnt[t];
    int sc = v;
#pragma unroll
    for (int off = 1; off < 64; off <<= 1) {
        int u = __shfl_up(sc, off, 64);
        if (lane >= off) sc += u;
    }
    if (lane == 63) wsum[w] = sc;
    __syncthreads();
    int wpre = 0;
    for (int j = 0; j < w; ++j) wpre += wsum[j];
    int excl = wpre + sc - v;
    pre[t] = excl;
    int n = (b << BW_SH) + t;
    if (n < N_NODES) rows[n] = base + excl;
    __syncthreads();
    for (int i = base + t; i < end; i += 256) {
        unsigned u = bkt[i];
        int loc = (u >> 17) & 255;
        int r = atomicAdd(&rnk[loc], 1);
        outarr[base + pre[loc] + r] = (int)(u & 0x1FFFFu);
    }
}

// -------- src-side segment softmax stats: per-node (max, sum) only ----------
__global__ __launch_bounds__(256) void k_seg_src(const int* __restrict__ dsts_s,
                                                 const int* __restrict__ rows_s,
                                                 const float* __restrict__ el,
                                                 const float* __restrict__ er,
                                                 float2* __restrict__ mssrc) {
    int wid = threadIdx.x >> 6, lane = threadIdx.x & 63;
    int n = blockIdx.x * 4 + wid;
    if (n >= N_NODES) return;
    int rs = rows_s[n], re = rows_s[n + 1];
    if (rs >= re) return;
    float el0 = el[n * 3 + 0], el1 = el[n * 3 + 1], el2 = el[n * 3 + 2];
    bool single = (re - rs) <= 64;
    float m0 = -INFINITY, m1 = -INFINITY, m2 = -INFINITY;
    float c0 = -INFINITY, c1 = -INFINITY, c2 = -INFINITY;
    for (int p0 = rs; p0 < re; p0 += 64) {
        int p = p0 + lane;
        bool act = p < re;
        int d = act ? dsts_s[p] : 0;
        float t0 = act ? leaky(el0 + er[d * 3 + 0]) : -INFINITY;
        float t1 = act ? leaky(el1 + er[d * 3 + 1]) : -INFINITY;
        float t2 = act ? leaky(el2 + er[d * 3 + 2]) : -INFINITY;
        if (single) { c0 = t0; c1 = t1; c2 = t2; }
        m0 = fmaxf(m0, t0); m1 = fmaxf(m1, t1); m2 = fmaxf(m2, t2);
    }
#pragma unroll
    for (int off = 1; off < 64; off <<= 1) {
        m0 = fmaxf(m0, __shfl_xor(m0, off));
        m1 = fmaxf(m1, __shfl_xor(m1, off));
        m2 = fmaxf(m2, __shfl_xor(m2, off));
    }
    float s0 = 0, s1 = 0, s2 = 0;
    if (single) {
        bool act = (rs + lane) < re;
        s0 = act ? expf(c0 - m0) : 0.f;
        s1 = act ? expf(c1 - m1) : 0.f;
        s2 = act ? expf(c2 - m2) : 0.f;
    } else {
        for (int p0 = rs; p0 < re; p0 += 64) {
            int p = p0 + lane;
            if (p < re) {
                int d = dsts_s[p];
                s0 += expf(leaky(el0 + er[d * 3 + 0]) - m0);
                s1 += expf(leaky(el1 + er[d * 3 + 1]) - m1);
                s2 += expf(leaky(el2 + er[d * 3 + 2]) - m2);
            }
        }
    }
#pragma unroll
    for (int off = 1; off < 64; off <<= 1) {
        s0 += __shfl_xor(s0, off);
        s1 += __shfl_xor(s1, off);
        s2 += __shfl_xor(s2, off);
    }
    if (lane == 0) {
        mssrc[n * 3 + 0] = make_float2(m0, s0);
        mssrc[n * 3 + 1] = make_float2(m1, s1);
        mssrc[n * 3 + 2] = make_float2(m2, s2);
    }
}

// -------- dst-side stats + fused symmetric attention coefficient ----------
__global__ __launch_bounds__(256) void k_seg_dst_attn(const int* __restrict__ srcs_d,
                                                      const int* __restrict__ rows_d,
                                                      const float* __restrict__ el,
                                                      const float* __restrict__ er,
                                                      const float2* __restrict__ mssrc,
                                                      float* __restrict__ a_sorted) {
    int wid = threadIdx.x >> 6, lane = threadIdx.x & 63;
    int n = blockIdx.x * 4 + wid;
    if (n >= N_NODES) return;
    int rs = rows_d[n], re = rows_d[n + 1];
    if (rs >= re) return;
    float er0 = er[n * 3 + 0], er1 = er[n * 3 + 1], er2 = er[n * 3 + 2];
    bool single = (re - rs) <= 64;
    float m0 = -INFINITY, m1 = -INFINITY, m2 = -INFINITY;
    float c0 = -INFINITY, c1 = -INFINITY, c2 = -INFINITY;
    int scache = 0;
    for (int p0 = rs; p0 < re; p0 += 64) {
        int p = p0 + lane;
        bool act = p < re;
        int s = act ? srcs_d[p] : 0;
        if (single) scache = s;
        float t0 = act ? leaky(el[s * 3 + 0] + er0) : -INFINITY;
        float t1 = act ? leaky(el[s * 3 + 1] + er1) : -INFINITY;
        float t2 = act ? leaky(el[s * 3 + 2] + er2) : -INFINITY;
        if (single) { c0 = t0; c1 = t1; c2 = t2; }
        m0 = fmaxf(m0, t0); m1 = fmaxf(m1, t1); m2 = fmaxf(m2, t2);
    }
#pragma unroll
    for (int off = 1; off < 64; off <<= 1) {
        m0 = fmaxf(m0, __shfl_xor(m0, off));
        m1 = fmaxf(m1, __shfl_xor(m1, off));
        m2 = fmaxf(m2, __shfl_xor(m2, off));
    }
    float s0 = 0, s1 = 0, s2 = 0;
    if (single) {
        bool act = (rs + lane) < re;
        s0 = act ? expf(c0 - m0) : 0.f;
        s1 = act ? expf(c1 - m1) : 0.f;
        s2 = act ? expf(c2 - m2) : 0.f;
    } else {
        for (int p0 = rs; p0 < re; p0 += 64) {
            int p = p0 + lane;
            if (p < re) {
                int s = srcs_d[p];
                s0 += expf(leaky(el[s * 3 + 0] + er0) - m0);
                s1 += expf(leaky(el[s * 3 + 1] + er1) - m1);
                s2 += expf(leaky(el[s * 3 + 2] + er2) - m2);
            }
        }
    }
#pragma unroll
    for (int off = 1; off < 64; off <<= 1) {
        s0 += __shfl_xor(s0, off);
        s1 += __shfl_xor(s1, off);
        s2 += __shfl_xor(s2, off);
    }
    float i0 = 1.f / s0, i1 = 1.f / s1, i2 = 1.f / s2;
    for (int p0 = rs; p0 < re; p0 += 64) {
        int p = p0 + lane;
        if (p >= re) break;
        int s = single ? scache : srcs_d[p];
        float t0, t1, t2;
        if (single) { t0 = c0; t1 = c1; t2 = c2; }
        else {
            t0 = leaky(el[s * 3 + 0] + er0);
            t1 = leaky(el[s * 3 + 1] + er1);
            t2 = leaky(el[s * 3 + 2] + er2);
        }
        float2 a0 = mssrc[s * 3 + 0], a1 = mssrc[s * 3 + 1], a2 = mssrc[s * 3 + 2];
        float d0 = fmaxf(expf(t0 - m0) * i0, EPS_V);
        float d1 = fmaxf(expf(t1 - m1) * i1, EPS_V);
        float d2 = fmaxf(expf(t2 - m2) * i2, EPS_V);
        float u0 = fmaxf(expf(t0 - a0.x) / a0.y, EPS_V);
        float u1 = fmaxf(expf(t1 - a1.x) / a1.y, EPS_V);
        float u2 = fmaxf(expf(t2 - a2.x) / a2.y, EPS_V);
        a_sorted[p * 3 + 0] = sqrtf(d0 * u0);
        a_sorted[p * 3 + 1] = sqrtf(d1 * u1);
        a_sorted[p * 3 + 2] = sqrtf(d2 * u2);
    }
}

// ---------------- one diffusion hop (bf16 features, f32 accumulate) ----------------
__global__ __launch_bounds__(256) void k_hop(const bf16* __restrict__ cur,
                                             const float* __restrict__ a_sorted,
                                             const int* __restrict__ rowstart,
                                             const int* __restrict__ src_sorted,
                                             bf16* __restrict__ out) {
    int wid = threadIdx.x >> 6, lane = threadIdx.x & 63;
    int n = blockIdx.x * 4 + wid;
    if (n >= N_NODES) return;
    if (lane >= HD) return;
    int h = lane >> 4;
    int rs = rowstart[n], re = rowstart[n + 1];
    float acc = 0.f;
    for (int p = rs; p < re; ++p) {
        int s = src_sorted[p];
        float a = a_sorted[p * HH + h];
        acc += a * b2f(cur[s * HD + lane]);
    }
    out[n * HD + lane] = __float2bfloat16(acc);
}

// ---------------- feat_trans + hop attention + output ----------------
__global__ void k_final(const float* __restrict__ ft, const bf16* __restrict__ cur1,
                        const bf16* __restrict__ cur2, const bf16* __restrict__ cur3,
                        const float* __restrict__ hop_l, const float* __restrict__ hop_r,
                        const float* __restrict__ pos_emb, const float* __restrict__ scales,
                        const float* __restrict__ offs, const float* __restrict__ bias,
                        float* __restrict__ out) {
    int i = blockIdx.x * blockDim.x + threadIdx.x;
    if (i >= N_NODES * HH) return;
    int h = i % HH;
    float hk[4][DD];
#pragma unroll
    for (int k = 0; k < 4; ++k) {
        float x[DD];
#pragma unroll
        for (int d = 0; d < DD; ++d) {
            x[d] = (k == 0) ? ft[(size_t)i * DD + d]
                 : (k == 1) ? b2f(cur1[(size_t)i * DD + d])
                 : (k == 2) ? b2f(cur2[(size_t)i * DD + d])
                            : b2f(cur3[(size_t)i * DD + d]);
        }
        float m = 0.f;
#pragma unroll
        for (int d = 0; d < DD; ++d) m += x[d];
        m *= (1.f / DD);
        float v2 = 0.f;
#pragma unroll
        for (int d = 0; d < DD; ++d) {
            float c = x[d] - m;
            v2 += c * c;
        }
        v2 = v2 * (1.f / DD) + EPS_V;
        float rsq = rsqrtf(v2);
#pragma unroll
        for (int d = 0; d < DD; ++d) {
            hk[k][d] = (x[d] - m) * scales[k * HD + h * DD + d] * rsq +
                       offs[k * HD + h * DD + d] + pos_emb[h * 64 + k * DD + d];
        }
    }
    float al = 0.f;
#pragma unroll
    for (int d = 0; d < DD; ++d) al += hk[0][d] * hop_l[h * DD + d];
    float ar[3], mx = -1e30f;
#pragma unroll
    for (int k = 0; k < 3; ++k) {
        float s = 0.f;
#pragma unroll
        for (int d = 0; d < DD; ++d) s += hk[k + 1][d] * hop_r[h * DD + d];
        ar[k] = leaky(s + al);
        mx = fmaxf(mx, ar[k]);
    }
    float den = 0.f, wgt[3];
#pragma unroll
    for (int k = 0; k < 3; ++k) {
        wgt[k] = expf(ar[k] - mx);
        den += wgt[k];
    }
#pragma unroll
    for (int k = 0; k < 3; ++k) wgt[k] /= den;
#pragma unroll
    for (int d = 0; d < DD; ++d) {
        float o = hk[1][d] * wgt[0] + hk[2][d] * wgt[1] + hk[3][d] * wgt[2] +
                  bias[h * DD + d];
        out[i * DD + d] = o;
    }
}

// ---------------- workspace layout (4B-element offsets) ----------------
#define OFF_FT     0u          // 4.8M f32
#define OFF_FT16   4800000u    // 2.4M slots (bf16 x 4.8M)
#define OFF_EL     7200000u    // 300k
#define OFF_ER     7500000u    // 300k
#define OFF_MSSRC  7800000u    // 600k (float2 x 300k)
#define OFF_BCNT   8400000u    // 1600: bcnt_d@0, bcnt_s@400, bfill_d@800, bfill_s@1200 [memset]
#define OFF_BBASE  8401600u    // 800: bbase_d@0 (NB+1), bbase_s@400
#define OFF_ROWD   8402400u    // 100001
#define OFF_ROWS_  8502402u    // 100001
#define OFF_BKTD   8602404u    // 1.6M u32
#define OFF_BKTS   10202404u   // 1.6M u32
#define OFF_SRCSD  11802404u   // 1.6M
#define OFF_DSTSS  13402404u   // 1.6M
#define OFF_ASORT  15002404u   // 4.8M
#define OFF_CUR1   19802404u   // 2.4M slots
#define OFF_CUR2   22202404u
#define OFF_CUR3   24602404u
#define WS_FLOATS  27002404u   // ~108 MB

extern "C" void kernel_launch(void* const* d_in, const int* in_sizes, int n_in,
                              void* d_out, int out_size, void* d_ws, size_t ws_size,
                              hipStream_t stream) {
    if (ws_size < (size_t)WS_FLOATS * 4) return;

    const float* feat   = (const float*)d_in[0];
    const int*   src    = (const int*)d_in[1];
    const int*   dst    = (const int*)d_in[2];
    const float* fc_W   = (const float*)d_in[3];
    const float* attn_l = (const float*)d_in[4];
    const float* attn_r = (const float*)d_in[5];
    const float* hop_l  = (const float*)d_in[6];
    const float* hop_r  = (const float*)d_in[7];
    const float* pos    = (const float*)d_in[8];
    const float* scal   = (const float*)d_in[9];
    const float* offs   = (const float*)d_in[10];
    const float* bias   = (const float*)d_in[11];
    float* out = (float*)d_out;

    float* ws = (float*)d_ws;
    float*    ft      = ws + OFF_FT;
    bf16*     ft16    = (bf16*)(ws + OFF_FT16);
    float*    el      = ws + OFF_EL;
    float*    er      = ws + OFF_ER;
    float2*   mssrc   = (float2*)(ws + OFF_MSSRC);
    int*      bcnt_d  = (int*)(ws + OFF_BCNT);
    int*      bcnt_s  = bcnt_d + 400;
    int*      bfill_d = bcnt_d + 800;
    int*      bfill_s = bcnt_d + 1200;
    int*      bbase_d = (int*)(ws + OFF_BBASE);
    int*      bbase_s = bbase_d + 400;
    int*      rows_d  = (int*)(ws + OFF_ROWD);
    int*      rows_s  = (int*)(ws + OFF_ROWS_);
    unsigned* bkt_d   = (unsigned*)(ws + OFF_BKTD);
    unsigned* bkt_s   = (unsigned*)(ws + OFF_BKTS);
    int*      srcs_d  = (int*)(ws + OFF_SRCSD);
    int*      dsts_s  = (int*)(ws + OFF_DSTSS);
    float*    a_sorted= ws + OFF_ASORT;
    bf16*     cur1    = (bf16*)(ws + OFF_CUR1);
    bf16*     cur2    = (bf16*)(ws + OFF_CUR2);
    bf16*     cur3    = (bf16*)(ws + OFF_CUR3);

    hipMemsetAsync(ws + OFF_BCNT, 0, 1600 * 4, stream);

    k_gemm<<<(N_NODES + GR - 1) / GR, 256, 0, stream>>>(feat, fc_W, ft, ft16);
    k_eler<<<(N_NODES * HH + 255) / 256, 256, 0, stream>>>(ft, attn_l, attn_r, el, er);

    k_bhist<<<64, 256, 0, stream>>>(src, dst, bcnt_s, bcnt_d);
    k_bscan<<<2, 512, 0, stream>>>(bcnt_d, bbase_d, bcnt_s, bbase_s, rows_d, rows_s);
    k_msplit<<<(N_EDGES + MS_T - 1) / MS_T, 256, 0, stream>>>(src, dst, bbase_d, bbase_s,
                                                              bfill_d, bfill_s, bkt_d, bkt_s);
    k_bfinal<<<NB, 256, 0, stream>>>(bkt_d, bbase_d, rows_d, srcs_d);
    k_bfinal<<<NB, 256, 0, stream>>>(bkt_s, bbase_s, rows_s, dsts_s);

    k_seg_src<<<(N_NODES + 3) / 4, 256, 0, stream>>>(dsts_s, rows_s, el, er, mssrc);
    k_seg_dst_attn<<<(N_NODES + 3) / 4, 256, 0, stream>>>(srcs_d, rows_d, el, er,
                                                          mssrc, a_sorted);
    k_hop<<<(N_NODES + 3) / 4, 256, 0, stream>>>(ft16, a_sorted, rows_d, srcs_d, cur1);
    k_hop<<<(N_NODES + 3) / 4, 256, 0, stream>>>(cur1, a_sorted, rows_d, srcs_d, cur2);
    k_hop<<<(N_NODES + 3) / 4, 256, 0, stream>>>(cur2, a_sorted, rows_d, srcs_d, cur3);
    k_final<<<(N_NODES * HH + 255) / 256, 256, 0, stream>>>(ft, cur1, cur2, cur3, hop_l,
                                                            hop_r, pos, scal, offs, bias,
                                                            out);
}

// Round 6
// 543.827 us; speedup vs baseline: 3.1919x; 1.4071x over previous
//
#include <hip/hip_runtime.h>
#include <hip/hip_bf16.h>

typedef __hip_bfloat16 bf16;

#define N_NODES 100000
#define N_EDGES 1600000
#define IN_F    128
#define HH      3      // heads
#define DD      16     // out feats per head
#define HD      48     // HH*DD
#define NEG_SLOPE 0.2f
#define EPS_V   1e-9f

#define NB      391    // ceil(N_NODES / 256) buckets
#define BW_SH   8      // bucket = node >> 8 (256 nodes per bucket)
#define MS_T    8192   // edges per multisplit workgroup

__device__ __forceinline__ float leaky(float x) { return x >= 0.f ? x : NEG_SLOPE * x; }
__device__ __forceinline__ float b2f(bf16 x) { return __bfloat162float(x); }

// ---------------- GEMM: ft[N,48] = feat[N,128] @ W[128,48]; also emits bf16 copy -------
#define GR 32
__global__ __launch_bounds__(256) void k_gemm(const float* __restrict__ feat,
                                              const float* __restrict__ W,
                                              float* __restrict__ ft,
                                              bf16* __restrict__ ft16) {
    __shared__ float Ws[IN_F][HD];
    __shared__ float Fs[GR][IN_F + 1];
    int t = threadIdx.x;
    for (int i = t; i < IN_F * HD; i += 256) Ws[i / HD][i % HD] = W[i];
    int row0 = blockIdx.x * GR;
    for (int i = t; i < GR * IN_F; i += 256) {
        int r = i >> 7, c = i & 127;
        int gr = row0 + r;
        Fs[r][c] = (gr < N_NODES) ? feat[gr * IN_F + c] : 0.f;
    }
    __syncthreads();
    int r = t >> 3, cg = t & 7;
    float acc[6] = {0, 0, 0, 0, 0, 0};
    for (int k = 0; k < IN_F; ++k) {
        float a = Fs[r][k];
#pragma unroll
        for (int j = 0; j < 6; ++j) acc[j] += a * Ws[k][cg * 6 + j];
    }
    int gr = row0 + r;
    if (gr < N_NODES) {
#pragma unroll
        for (int j = 0; j < 6; ++j) {
            ft[gr * HD + cg * 6 + j] = acc[j];
            ft16[gr * HD + cg * 6 + j] = __float2bfloat16(acc[j]);
        }
    }
}

// ---------------- el/er ----------------
__global__ void k_eler(const float* __restrict__ ft, const float* __restrict__ attn_l,
                       const float* __restrict__ attn_r, float* __restrict__ el,
                       float* __restrict__ er) {
    int i = blockIdx.x * blockDim.x + threadIdx.x;
    if (i >= N_NODES * HH) return;
    int h = i % HH;
    float sl = 0.f, sr = 0.f;
#pragma unroll
    for (int d = 0; d < DD; ++d) {
        float v = ft[i * DD + d];
        sl += v * attn_l[h * DD + d];
        sr += v * attn_r[h * DD + d];
    }
    el[i] = sl;
    er[i] = sr;
}

// ---------------- K1: per-bucket histograms (LDS-privatized) ----------------
__global__ __launch_bounds__(256) void k_bhist(const int* __restrict__ src,
                                               const int* __restrict__ dst,
                                               int* __restrict__ bcnt_s,
                                               int* __restrict__ bcnt_d) {
    __shared__ int ls[NB], ld_[NB];
    int t = threadIdx.x;
    for (int i = t; i < NB; i += 256) { ls[i] = 0; ld_[i] = 0; }
    __syncthreads();
    for (int e = blockIdx.x * 256 + t; e < N_EDGES; e += gridDim.x * 256) {
        atomicAdd(&ld_[dst[e] >> BW_SH], 1);
        atomicAdd(&ls[src[e] >> BW_SH], 1);
    }
    __syncthreads();
    for (int i = t; i < NB; i += 256) {
        if (ld_[i]) atomicAdd(&bcnt_d[i], ld_[i]);
        if (ls[i]) atomicAdd(&bcnt_s[i], ls[i]);
    }
}

// ---------------- K2: scan bucket counts -> bucket bases (+ sentinels) -------------
__global__ __launch_bounds__(512) void k_bscan(const int* __restrict__ bcnt_d,
                                               int* __restrict__ bbase_d,
                                               const int* __restrict__ bcnt_s,
                                               int* __restrict__ bbase_s,
                                               int* __restrict__ rows_d,
                                               int* __restrict__ rows_s) {
    __shared__ int buf[512];
    const int* c = blockIdx.x ? bcnt_s : bcnt_d;
    int* o = blockIdx.x ? bbase_s : bbase_d;
    int t = threadIdx.x;
    int v = (t < NB) ? c[t] : 0;
    buf[t] = v;
    __syncthreads();
    for (int off = 1; off < 512; off <<= 1) {
        int u = (t >= off) ? buf[t - off] : 0;
        __syncthreads();
        buf[t] += u;
        __syncthreads();
    }
    if (t < NB) o[t] = buf[t] - v;      // exclusive
    if (t == NB - 1) o[NB] = buf[t];    // == N_EDGES
    if (t == 0) {
        if (blockIdx.x) rows_s[N_NODES] = N_EDGES;
        else            rows_d[N_NODES] = N_EDGES;
    }
}

// ---------------- K3: multisplit — bucket edges for both directions ----------------
// bkt_d entry: s | ((d & 255) << 17)   (bucketed by d)
// bkt_s entry: d | ((s & 255) << 17)   (bucketed by s)
__global__ __launch_bounds__(256) void k_msplit(const int* __restrict__ src,
                                                const int* __restrict__ dst,
                                                const int* __restrict__ bbase_d,
                                                const int* __restrict__ bbase_s,
                                                int* __restrict__ bfill_d,
                                                int* __restrict__ bfill_s,
                                                unsigned* __restrict__ bkt_d,
                                                unsigned* __restrict__ bkt_s) {
    __shared__ int lcD[NB], lcS[NB], wbD[NB], wbS[NB], rkD[NB], rkS[NB];
    int t = threadIdx.x;
    int e0 = blockIdx.x * MS_T;
    int e1 = min(e0 + MS_T, N_EDGES);
    for (int i = t; i < NB; i += 256) { lcD[i] = 0; lcS[i] = 0; rkD[i] = 0; rkS[i] = 0; }
    __syncthreads();
    for (int e = e0 + t; e < e1; e += 256) {
        atomicAdd(&lcD[dst[e] >> BW_SH], 1);
        atomicAdd(&lcS[src[e] >> BW_SH], 1);
    }
    __syncthreads();
    for (int i = t; i < NB; i += 256) {
        wbD[i] = bbase_d[i] + (lcD[i] ? atomicAdd(&bfill_d[i], lcD[i]) : 0);
        wbS[i] = bbase_s[i] + (lcS[i] ? atomicAdd(&bfill_s[i], lcS[i]) : 0);
    }
    __syncthreads();
    for (int e = e0 + t; e < e1; e += 256) {
        int s = src[e], d = dst[e];
        int bd = d >> BW_SH, bs = s >> BW_SH;
        int rd = atomicAdd(&rkD[bd], 1);
        int rs = atomicAdd(&rkS[bs], 1);
        bkt_d[wbD[bd] + rd] = (unsigned)s | ((unsigned)(d & 255) << 17);
        bkt_s[wbS[bs] + rs] = (unsigned)d | ((unsigned)(s & 255) << 17);
    }
}

// ---------------- K4: per-bucket CSR finalize (rows + payload scatter) --------------
__global__ __launch_bounds__(256) void k_bfinal(const unsigned* __restrict__ bkt,
                                                const int* __restrict__ bbase,
                                                int* __restrict__ rows,
                                                int* __restrict__ outarr) {
    __shared__ int cnt[256], pre[256], rnk[256], wsum[4];
    int b = blockIdx.x, t = threadIdx.x;
    int base = bbase[b], end = bbase[b + 1];
    cnt[t] = 0; rnk[t] = 0;
    __syncthreads();
    for (int i = base + t; i < end; i += 256)
        atomicAdd(&cnt[(bkt[i] >> 17) & 255], 1);
    __syncthreads();
    int lane = t & 63, w = t >> 6;
    int v = cnt[t];
    int sc = v;
#pragma unroll
    for (int off = 1; off < 64; off <<= 1) {
        int u = __shfl_up(sc, off, 64);
        if (lane >= off) sc += u;
    }
    if (lane == 63) wsum[w] = sc;
    __syncthreads();
    int wpre = 0;
    for (int j = 0; j < w; ++j) wpre += wsum[j];
    int excl = wpre + sc - v;
    pre[t] = excl;
    int n = (b << BW_SH) + t;
    if (n < N_NODES) rows[n] = base + excl;
    __syncthreads();
    for (int i = base + t; i < end; i += 256) {
        unsigned u = bkt[i];
        int loc = (u >> 17) & 255;
        int r = atomicAdd(&rnk[loc], 1);
        outarr[base + pre[loc] + r] = (int)(u & 0x1FFFFu);
    }
}

// -------- src-side segment softmax stats: per-node (max, sum) only ----------
__global__ __launch_bounds__(256) void k_seg_src(const int* __restrict__ dsts_s,
                                                 const int* __restrict__ rows_s,
                                                 const float* __restrict__ el,
                                                 const float* __restrict__ er,
                                                 float2* __restrict__ mssrc) {
    int wid = threadIdx.x >> 6, lane = threadIdx.x & 63;
    int n = blockIdx.x * 4 + wid;
    if (n >= N_NODES) return;
    int rs = rows_s[n], re = rows_s[n + 1];
    if (rs >= re) return;
    float el0 = el[n * 3 + 0], el1 = el[n * 3 + 1], el2 = el[n * 3 + 2];
    bool single = (re - rs) <= 64;
    float m0 = -INFINITY, m1 = -INFINITY, m2 = -INFINITY;
    float c0 = -INFINITY, c1 = -INFINITY, c2 = -INFINITY;
    for (int p0 = rs; p0 < re; p0 += 64) {
        int p = p0 + lane;
        bool act = p < re;
        int d = act ? dsts_s[p] : 0;
        float t0 = act ? leaky(el0 + er[d * 3 + 0]) : -INFINITY;
        float t1 = act ? leaky(el1 + er[d * 3 + 1]) : -INFINITY;
        float t2 = act ? leaky(el2 + er[d * 3 + 2]) : -INFINITY;
        if (single) { c0 = t0; c1 = t1; c2 = t2; }
        m0 = fmaxf(m0, t0); m1 = fmaxf(m1, t1); m2 = fmaxf(m2, t2);
    }
#pragma unroll
    for (int off = 1; off < 64; off <<= 1) {
        m0 = fmaxf(m0, __shfl_xor(m0, off));
        m1 = fmaxf(m1, __shfl_xor(m1, off));
        m2 = fmaxf(m2, __shfl_xor(m2, off));
    }
    float s0 = 0, s1 = 0, s2 = 0;
    if (single) {
        bool act = (rs + lane) < re;
        s0 = act ? expf(c0 - m0) : 0.f;
        s1 = act ? expf(c1 - m1) : 0.f;
        s2 = act ? expf(c2 - m2) : 0.f;
    } else {
        for (int p0 = rs; p0 < re; p0 += 64) {
            int p = p0 + lane;
            if (p < re) {
                int d = dsts_s[p];
                s0 += expf(leaky(el0 + er[d * 3 + 0]) - m0);
                s1 += expf(leaky(el1 + er[d * 3 + 1]) - m1);
                s2 += expf(leaky(el2 + er[d * 3 + 2]) - m2);
            }
        }
    }
#pragma unroll
    for (int off = 1; off < 64; off <<= 1) {
        s0 += __shfl_xor(s0, off);
        s1 += __shfl_xor(s1, off);
        s2 += __shfl_xor(s2, off);
    }
    if (lane == 0) {
        mssrc[n * 3 + 0] = make_float2(m0, s0);
        mssrc[n * 3 + 1] = make_float2(m1, s1);
        mssrc[n * 3 + 2] = make_float2(m2, s2);
    }
}

// -------- dst-side stats + fused symmetric attention coefficient ----------
__global__ __launch_bounds__(256) void k_seg_dst_attn(const int* __restrict__ srcs_d,
                                                      const int* __restrict__ rows_d,
                                                      const float* __restrict__ el,
                                                      const float* __restrict__ er,
                                                      const float2* __restrict__ mssrc,
                                                      float* __restrict__ a_sorted) {
    int wid = threadIdx.x >> 6, lane = threadIdx.x & 63;
    int n = blockIdx.x * 4 + wid;
    if (n >= N_NODES) return;
    int rs = rows_d[n], re = rows_d[n + 1];
    if (rs >= re) return;
    float er0 = er[n * 3 + 0], er1 = er[n * 3 + 1], er2 = er[n * 3 + 2];
    bool single = (re - rs) <= 64;
    float m0 = -INFINITY, m1 = -INFINITY, m2 = -INFINITY;
    float c0 = -INFINITY, c1 = -INFINITY, c2 = -INFINITY;
    int scache = 0;
    for (int p0 = rs; p0 < re; p0 += 64) {
        int p = p0 + lane;
        bool act = p < re;
        int s = act ? srcs_d[p] : 0;
        if (single) scache = s;
        float t0 = act ? leaky(el[s * 3 + 0] + er0) : -INFINITY;
        float t1 = act ? leaky(el[s * 3 + 1] + er1) : -INFINITY;
        float t2 = act ? leaky(el[s * 3 + 2] + er2) : -INFINITY;
        if (single) { c0 = t0; c1 = t1; c2 = t2; }
        m0 = fmaxf(m0, t0); m1 = fmaxf(m1, t1); m2 = fmaxf(m2, t2);
    }
#pragma unroll
    for (int off = 1; off < 64; off <<= 1) {
        m0 = fmaxf(m0, __shfl_xor(m0, off));
        m1 = fmaxf(m1, __shfl_xor(m1, off));
        m2 = fmaxf(m2, __shfl_xor(m2, off));
    }
    float s0 = 0, s1 = 0, s2 = 0;
    if (single) {
        bool act = (rs + lane) < re;
        s0 = act ? expf(c0 - m0) : 0.f;
        s1 = act ? expf(c1 - m1) : 0.f;
        s2 = act ? expf(c2 - m2) : 0.f;
    } else {
        for (int p0 = rs; p0 < re; p0 += 64) {
            int p = p0 + lane;
            if (p < re) {
                int s = srcs_d[p];
                s0 += expf(leaky(el[s * 3 + 0] + er0) - m0);
                s1 += expf(leaky(el[s * 3 + 1] + er1) - m1);
                s2 += expf(leaky(el[s * 3 + 2] + er2) - m2);
            }
        }
    }
#pragma unroll
    for (int off = 1; off < 64; off <<= 1) {
        s0 += __shfl_xor(s0, off);
        s1 += __shfl_xor(s1, off);
        s2 += __shfl_xor(s2, off);
    }
    float i0 = 1.f / s0, i1 = 1.f / s1, i2 = 1.f / s2;
    for (int p0 = rs; p0 < re; p0 += 64) {
        int p = p0 + lane;
        if (p >= re) break;
        int s = single ? scache : srcs_d[p];
        float t0, t1, t2;
        if (single) { t0 = c0; t1 = c1; t2 = c2; }
        else {
            t0 = leaky(el[s * 3 + 0] + er0);
            t1 = leaky(el[s * 3 + 1] + er1);
            t2 = leaky(el[s * 3 + 2] + er2);
        }
        float2 a0 = mssrc[s * 3 + 0], a1 = mssrc[s * 3 + 1], a2 = mssrc[s * 3 + 2];
        float d0 = fmaxf(expf(t0 - m0) * i0, EPS_V);
        float d1 = fmaxf(expf(t1 - m1) * i1, EPS_V);
        float d2 = fmaxf(expf(t2 - m2) * i2, EPS_V);
        float u0 = fmaxf(expf(t0 - a0.x) / a0.y, EPS_V);
        float u1 = fmaxf(expf(t1 - a1.x) / a1.y, EPS_V);
        float u2 = fmaxf(expf(t2 - a2.x) / a2.y, EPS_V);
        a_sorted[p * 3 + 0] = sqrtf(d0 * u0);
        a_sorted[p * 3 + 1] = sqrtf(d1 * u1);
        a_sorted[p * 3 + 2] = sqrtf(d2 * u2);
    }
}

// ------- one diffusion hop: 8-deep software-pipelined gather (bf16, f32 accum) -------
__global__ __launch_bounds__(256) void k_hop(const bf16* __restrict__ cur,
                                             const float* __restrict__ a_sorted,
                                             const int* __restrict__ rowstart,
                                             const int* __restrict__ src_sorted,
                                             bf16* __restrict__ out) {
    int wid = threadIdx.x >> 6, lane = threadIdx.x & 63;
    int n = blockIdx.x * 4 + wid;
    if (n >= N_NODES) return;
    if (lane >= HD) return;
    int h = lane >> 4;
    int rs = rowstart[n], re = rowstart[n + 1];
    float acc = 0.f;
    int p = rs;
    for (; p + 8 <= re; p += 8) {
        int s[8];
#pragma unroll
        for (int j = 0; j < 8; ++j) s[j] = src_sorted[p + j];
        float a[8];
#pragma unroll
        for (int j = 0; j < 8; ++j) a[j] = a_sorted[(p + j) * HH + h];
        float v[8];
#pragma unroll
        for (int j = 0; j < 8; ++j) v[j] = b2f(cur[s[j] * HD + lane]);
#pragma unroll
        for (int j = 0; j < 8; ++j) acc += a[j] * v[j];
    }
    if (p < re) {
        int cnt = re - p;
        int s[8];
#pragma unroll
        for (int j = 0; j < 8; ++j) s[j] = (j < cnt) ? src_sorted[p + j] : 0;
        float a[8];
#pragma unroll
        for (int j = 0; j < 8; ++j) a[j] = (j < cnt) ? a_sorted[(p + j) * HH + h] : 0.f;
        float v[8];
#pragma unroll
        for (int j = 0; j < 8; ++j) v[j] = (j < cnt) ? b2f(cur[s[j] * HD + lane]) : 0.f;
#pragma unroll
        for (int j = 0; j < 8; ++j) acc += a[j] * v[j];
    }
    out[n * HD + lane] = __float2bfloat16(acc);
}

// ---------------- feat_trans + hop attention + output ----------------
__global__ void k_final(const float* __restrict__ ft, const bf16* __restrict__ cur1,
                        const bf16* __restrict__ cur2, const bf16* __restrict__ cur3,
                        const float* __restrict__ hop_l, const float* __restrict__ hop_r,
                        const float* __restrict__ pos_emb, const float* __restrict__ scales,
                        const float* __restrict__ offs, const float* __restrict__ bias,
                        float* __restrict__ out) {
    int i = blockIdx.x * blockDim.x + threadIdx.x;
    if (i >= N_NODES * HH) return;
    int h = i % HH;
    float hk[4][DD];
#pragma unroll
    for (int k = 0; k < 4; ++k) {
        float x[DD];
#pragma unroll
        for (int d = 0; d < DD; ++d) {
            x[d] = (k == 0) ? ft[(size_t)i * DD + d]
                 : (k == 1) ? b2f(cur1[(size_t)i * DD + d])
                 : (k == 2) ? b2f(cur2[(size_t)i * DD + d])
                            : b2f(cur3[(size_t)i * DD + d]);
        }
        float m = 0.f;
#pragma unroll
        for (int d = 0; d < DD; ++d) m += x[d];
        m *= (1.f / DD);
        float v2 = 0.f;
#pragma unroll
        for (int d = 0; d < DD; ++d) {
            float c = x[d] - m;
            v2 += c * c;
        }
        v2 = v2 * (1.f / DD) + EPS_V;
        float rsq = rsqrtf(v2);
#pragma unroll
        for (int d = 0; d < DD; ++d) {
            hk[k][d] = (x[d] - m) * scales[k * HD + h * DD + d] * rsq +
                       offs[k * HD + h * DD + d] + pos_emb[h * 64 + k * DD + d];
        }
    }
    float al = 0.f;
#pragma unroll
    for (int d = 0; d < DD; ++d) al += hk[0][d] * hop_l[h * DD + d];
    float ar[3], mx = -1e30f;
#pragma unroll
    for (int k = 0; k < 3; ++k) {
        float s = 0.f;
#pragma unroll
        for (int d = 0; d < DD; ++d) s += hk[k + 1][d] * hop_r[h * DD + d];
        ar[k] = leaky(s + al);
        mx = fmaxf(mx, ar[k]);
    }
    float den = 0.f, wgt[3];
#pragma unroll
    for (int k = 0; k < 3; ++k) {
        wgt[k] = expf(ar[k] - mx);
        den += wgt[k];
    }
#pragma unroll
    for (int k = 0; k < 3; ++k) wgt[k] /= den;
#pragma unroll
    for (int d = 0; d < DD; ++d) {
        float o = hk[1][d] * wgt[0] + hk[2][d] * wgt[1] + hk[3][d] * wgt[2] +
                  bias[h * DD + d];
        out[i * DD + d] = o;
    }
}

// ---------------- workspace layout (4B-element offsets) ----------------
#define OFF_FT     0u          // 4.8M f32
#define OFF_FT16   4800000u    // 2.4M slots (bf16 x 4.8M)
#define OFF_EL     7200000u    // 300k
#define OFF_ER     7500000u    // 300k
#define OFF_MSSRC  7800000u    // 600k (float2 x 300k)
#define OFF_BCNT   8400000u    // 1600: bcnt_d@0, bcnt_s@400, bfill_d@800, bfill_s@1200 [memset]
#define OFF_BBASE  8401600u    // 800: bbase_d@0 (NB+1), bbase_s@400
#define OFF_ROWD   8402400u    // 100001
#define OFF_ROWS_  8502402u    // 100001
#define OFF_BKTD   8602404u    // 1.6M u32
#define OFF_BKTS   10202404u   // 1.6M u32
#define OFF_SRCSD  11802404u   // 1.6M
#define OFF_DSTSS  13402404u   // 1.6M
#define OFF_ASORT  15002404u   // 4.8M
#define OFF_CUR1   19802404u   // 2.4M slots
#define OFF_CUR2   22202404u
#define OFF_CUR3   24602404u
#define WS_FLOATS  27002404u   // ~108 MB

extern "C" void kernel_launch(void* const* d_in, const int* in_sizes, int n_in,
                              void* d_out, int out_size, void* d_ws, size_t ws_size,
                              hipStream_t stream) {
    if (ws_size < (size_t)WS_FLOATS * 4) return;

    const float* feat   = (const float*)d_in[0];
    const int*   src    = (const int*)d_in[1];
    const int*   dst    = (const int*)d_in[2];
    const float* fc_W   = (const float*)d_in[3];
    const float* attn_l = (const float*)d_in[4];
    const float* attn_r = (const float*)d_in[5];
    const float* hop_l  = (const float*)d_in[6];
    const float* hop_r  = (const float*)d_in[7];
    const float* pos    = (const float*)d_in[8];
    const float* scal   = (const float*)d_in[9];
    const float* offs   = (const float*)d_in[10];
    const float* bias   = (const float*)d_in[11];
    float* out = (float*)d_out;

    float* ws = (float*)d_ws;
    float*    ft      = ws + OFF_FT;
    bf16*     ft16    = (bf16*)(ws + OFF_FT16);
    float*    el      = ws + OFF_EL;
    float*    er      = ws + OFF_ER;
    float2*   mssrc   = (float2*)(ws + OFF_MSSRC);
    int*      bcnt_d  = (int*)(ws + OFF_BCNT);
    int*      bcnt_s  = bcnt_d + 400;
    int*      bfill_d = bcnt_d + 800;
    int*      bfill_s = bcnt_d + 1200;
    int*      bbase_d = (int*)(ws + OFF_BBASE);
    int*      bbase_s = bbase_d + 400;
    int*      rows_d  = (int*)(ws + OFF_ROWD);
    int*      rows_s  = (int*)(ws + OFF_ROWS_);
    unsigned* bkt_d   = (unsigned*)(ws + OFF_BKTD);
    unsigned* bkt_s   = (unsigned*)(ws + OFF_BKTS);
    int*      srcs_d  = (int*)(ws + OFF_SRCSD);
    int*      dsts_s  = (int*)(ws + OFF_DSTSS);
    float*    a_sorted= ws + OFF_ASORT;
    bf16*     cur1    = (bf16*)(ws + OFF_CUR1);
    bf16*     cur2    = (bf16*)(ws + OFF_CUR2);
    bf16*     cur3    = (bf16*)(ws + OFF_CUR3);

    hipMemsetAsync(ws + OFF_BCNT, 0, 1600 * 4, stream);

    k_gemm<<<(N_NODES + GR - 1) / GR, 256, 0, stream>>>(feat, fc_W, ft, ft16);
    k_eler<<<(N_NODES * HH + 255) / 256, 256, 0, stream>>>(ft, attn_l, attn_r, el, er);

    k_bhist<<<64, 256, 0, stream>>>(src, dst, bcnt_s, bcnt_d);
    k_bscan<<<2, 512, 0, stream>>>(bcnt_d, bbase_d, bcnt_s, bbase_s, rows_d, rows_s);
    k_msplit<<<(N_EDGES + MS_T - 1) / MS_T, 256, 0, stream>>>(src, dst, bbase_d, bbase_s,
                                                              bfill_d, bfill_s, bkt_d, bkt_s);
    k_bfinal<<<NB, 256, 0, stream>>>(bkt_d, bbase_d, rows_d, srcs_d);
    k_bfinal<<<NB, 256, 0, stream>>>(bkt_s, bbase_s, rows_s, dsts_s);

    k_seg_src<<<(N_NODES + 3) / 4, 256, 0, stream>>>(dsts_s, rows_s, el, er, mssrc);
    k_seg_dst_attn<<<(N_NODES + 3) / 4, 256, 0, stream>>>(srcs_d, rows_d, el, er,
                                                          mssrc, a_sorted);
    k_hop<<<(N_NODES + 3) / 4, 256, 0, stream>>>(ft16, a_sorted, rows_d, srcs_d, cur1);
    k_hop<<<(N_NODES + 3) / 4, 256, 0, stream>>>(cur1, a_sorted, rows_d, srcs_d, cur2);
    k_hop<<<(N_NODES + 3) / 4, 256, 0, stream>>>(cur2, a_sorted, rows_d, srcs_d, cur3);
    k_final<<<(N_NODES * HH + 255) / 256, 256, 0, stream>>>(ft, cur1, cur2, cur3, hop_l,
                                                            hop_r, pos, scal, offs, bias,
                                                            out);
}

// Round 7
// 493.574 us; speedup vs baseline: 3.5169x; 1.1018x over previous
//
#include <hip/hip_runtime.h>
#include <hip/hip_bf16.h>

typedef __hip_bfloat16 bf16;

#define N_NODES 100000
#define N_EDGES 1600000
#define IN_F    128
#define HH      3      // heads
#define DD      16     // out feats per head
#define HD      48     // HH*DD
#define NEG_SLOPE 0.2f
#define EPS_V   1e-9f

#define NB      391    // ceil(N_NODES / 256) buckets
#define BW_SH   8      // bucket = node >> 8 (256 nodes per bucket)
#define MS_T    8192   // edges per multisplit workgroup

__device__ __forceinline__ float leaky(float x) { return x >= 0.f ? x : NEG_SLOPE * x; }
__device__ __forceinline__ float b2f(bf16 x) { return __bfloat162float(x); }

// ------- GEMM: one row per thread, scalar(SMEM) W loads, 48 f32 accumulators -------
__global__ __launch_bounds__(256) void k_gemm(const float* __restrict__ feat,
                                              const float* __restrict__ W,
                                              float* __restrict__ ft,
                                              bf16* __restrict__ ft16) {
    int row = blockIdx.x * 256 + threadIdx.x;
    if (row >= N_NODES) return;
    float acc[HD];
#pragma unroll
    for (int c = 0; c < HD; ++c) acc[c] = 0.f;
    const float4* frow = (const float4*)(feat + (size_t)row * IN_F);
    for (int k4 = 0; k4 < IN_F / 4; ++k4) {
        float4 f = frow[k4];
        int k = k4 * 4;
        // W[k*HD+c] is wave-uniform -> scalar loads, no LDS needed
#pragma unroll
        for (int c = 0; c < HD; ++c) acc[c] += f.x * W[(k + 0) * HD + c];
#pragma unroll
        for (int c = 0; c < HD; ++c) acc[c] += f.y * W[(k + 1) * HD + c];
#pragma unroll
        for (int c = 0; c < HD; ++c) acc[c] += f.z * W[(k + 2) * HD + c];
#pragma unroll
        for (int c = 0; c < HD; ++c) acc[c] += f.w * W[(k + 3) * HD + c];
    }
    float4* orow = (float4*)(ft + (size_t)row * HD);
#pragma unroll
    for (int c = 0; c < HD / 4; ++c)
        orow[c] = make_float4(acc[4 * c], acc[4 * c + 1], acc[4 * c + 2], acc[4 * c + 3]);
    bf16* o16 = ft16 + (size_t)row * HD;
#pragma unroll
    for (int c = 0; c < HD; ++c) o16[c] = __float2bfloat16(acc[c]);
}

// ---------------- el/er ----------------
__global__ void k_eler(const float* __restrict__ ft, const float* __restrict__ attn_l,
                       const float* __restrict__ attn_r, float* __restrict__ el,
                       float* __restrict__ er) {
    int i = blockIdx.x * blockDim.x + threadIdx.x;
    if (i >= N_NODES * HH) return;
    int h = i % HH;
    float sl = 0.f, sr = 0.f;
#pragma unroll
    for (int d = 0; d < DD; ++d) {
        float v = ft[i * DD + d];
        sl += v * attn_l[h * DD + d];
        sr += v * attn_r[h * DD + d];
    }
    el[i] = sl;
    er[i] = sr;
}

// ---------------- K1: per-bucket histograms (LDS-privatized, int4 loads) -------------
__global__ __launch_bounds__(256) void k_bhist(const int4* __restrict__ src4,
                                               const int4* __restrict__ dst4,
                                               int* __restrict__ bcnt_s,
                                               int* __restrict__ bcnt_d) {
    __shared__ int ls[NB], ld_[NB];
    int t = threadIdx.x;
    for (int i = t; i < NB; i += 256) { ls[i] = 0; ld_[i] = 0; }
    __syncthreads();
    const int NE4 = N_EDGES / 4;
    for (int e = blockIdx.x * 256 + t; e < NE4; e += gridDim.x * 256) {
        int4 d = dst4[e];
        atomicAdd(&ld_[d.x >> BW_SH], 1);
        atomicAdd(&ld_[d.y >> BW_SH], 1);
        atomicAdd(&ld_[d.z >> BW_SH], 1);
        atomicAdd(&ld_[d.w >> BW_SH], 1);
        int4 s = src4[e];
        atomicAdd(&ls[s.x >> BW_SH], 1);
        atomicAdd(&ls[s.y >> BW_SH], 1);
        atomicAdd(&ls[s.z >> BW_SH], 1);
        atomicAdd(&ls[s.w >> BW_SH], 1);
    }
    __syncthreads();
    for (int i = t; i < NB; i += 256) {
        if (ld_[i]) atomicAdd(&bcnt_d[i], ld_[i]);
        if (ls[i]) atomicAdd(&bcnt_s[i], ls[i]);
    }
}

// ---------------- K2: scan bucket counts -> bucket bases (+ sentinels) -------------
__global__ __launch_bounds__(512) void k_bscan(const int* __restrict__ bcnt_d,
                                               int* __restrict__ bbase_d,
                                               const int* __restrict__ bcnt_s,
                                               int* __restrict__ bbase_s,
                                               int* __restrict__ rows_d,
                                               int* __restrict__ rows_s) {
    __shared__ int buf[512];
    const int* c = blockIdx.x ? bcnt_s : bcnt_d;
    int* o = blockIdx.x ? bbase_s : bbase_d;
    int t = threadIdx.x;
    int v = (t < NB) ? c[t] : 0;
    buf[t] = v;
    __syncthreads();
    for (int off = 1; off < 512; off <<= 1) {
        int u = (t >= off) ? buf[t - off] : 0;
        __syncthreads();
        buf[t] += u;
        __syncthreads();
    }
    if (t < NB) o[t] = buf[t] - v;      // exclusive
    if (t == NB - 1) o[NB] = buf[t];    // == N_EDGES
    if (t == 0) {
        if (blockIdx.x) rows_s[N_NODES] = N_EDGES;
        else            rows_d[N_NODES] = N_EDGES;
    }
}

// ---------------- K3: multisplit — bucket edges for both directions ----------------
__global__ __launch_bounds__(256) void k_msplit(const int* __restrict__ src,
                                                const int* __restrict__ dst,
                                                const int* __restrict__ bbase_d,
                                                const int* __restrict__ bbase_s,
                                                int* __restrict__ bfill_d,
                                                int* __restrict__ bfill_s,
                                                unsigned* __restrict__ bkt_d,
                                                unsigned* __restrict__ bkt_s) {
    __shared__ int lcD[NB], lcS[NB], wbD[NB], wbS[NB], rkD[NB], rkS[NB];
    int t = threadIdx.x;
    int e0 = blockIdx.x * MS_T;
    int e1 = min(e0 + MS_T, N_EDGES);
    for (int i = t; i < NB; i += 256) { lcD[i] = 0; lcS[i] = 0; rkD[i] = 0; rkS[i] = 0; }
    __syncthreads();
    for (int e = e0 + t; e < e1; e += 256) {
        atomicAdd(&lcD[dst[e] >> BW_SH], 1);
        atomicAdd(&lcS[src[e] >> BW_SH], 1);
    }
    __syncthreads();
    for (int i = t; i < NB; i += 256) {
        wbD[i] = bbase_d[i] + (lcD[i] ? atomicAdd(&bfill_d[i], lcD[i]) : 0);
        wbS[i] = bbase_s[i] + (lcS[i] ? atomicAdd(&bfill_s[i], lcS[i]) : 0);
    }
    __syncthreads();
    for (int e = e0 + t; e < e1; e += 256) {
        int s = src[e], d = dst[e];
        int bd = d >> BW_SH, bs = s >> BW_SH;
        int rd = atomicAdd(&rkD[bd], 1);
        int rs = atomicAdd(&rkS[bs], 1);
        bkt_d[wbD[bd] + rd] = (unsigned)s | ((unsigned)(d & 255) << 17);
        bkt_s[wbS[bs] + rs] = (unsigned)d | ((unsigned)(s & 255) << 17);
    }
}

// ---------------- K4: per-bucket CSR finalize (rows + payload scatter) --------------
__global__ __launch_bounds__(256) void k_bfinal(const unsigned* __restrict__ bkt,
                                                const int* __restrict__ bbase,
                                                int* __restrict__ rows,
                                                int* __restrict__ outarr) {
    __shared__ int cnt[256], pre[256], rnk[256], wsum[4];
    int b = blockIdx.x, t = threadIdx.x;
    int base = bbase[b], end = bbase[b + 1];
    cnt[t] = 0; rnk[t] = 0;
    __syncthreads();
    for (int i = base + t; i < end; i += 256)
        atomicAdd(&cnt[(bkt[i] >> 17) & 255], 1);
    __syncthreads();
    int lane = t & 63, w = t >> 6;
    int v = cnt[t];
    int sc = v;
#pragma unroll
    for (int off = 1; off < 64; off <<= 1) {
        int u = __shfl_up(sc, off, 64);
        if (lane >= off) sc += u;
    }
    if (lane == 63) wsum[w] = sc;
    __syncthreads();
    int wpre = 0;
    for (int j = 0; j < w; ++j) wpre += wsum[j];
    int excl = wpre + sc - v;
    pre[t] = excl;
    int n = (b << BW_SH) + t;
    if (n < N_NODES) rows[n] = base + excl;
    __syncthreads();
    for (int i = base + t; i < end; i += 256) {
        unsigned u = bkt[i];
        int loc = (u >> 17) & 255;
        int r = atomicAdd(&rnk[loc], 1);
        outarr[base + pre[loc] + r] = (int)(u & 0x1FFFFu);
    }
}

// -------- src-side segment softmax stats: per-node (max, sum) only ----------
__global__ __launch_bounds__(256) void k_seg_src(const int* __restrict__ dsts_s,
                                                 const int* __restrict__ rows_s,
                                                 const float* __restrict__ el,
                                                 const float* __restrict__ er,
                                                 float2* __restrict__ mssrc) {
    int wid = threadIdx.x >> 6, lane = threadIdx.x & 63;
    int n = blockIdx.x * 4 + wid;
    if (n >= N_NODES) return;
    int rs = rows_s[n], re = rows_s[n + 1];
    if (rs >= re) return;
    float el0 = el[n * 3 + 0], el1 = el[n * 3 + 1], el2 = el[n * 3 + 2];
    bool single = (re - rs) <= 64;
    float m0 = -INFINITY, m1 = -INFINITY, m2 = -INFINITY;
    float c0 = -INFINITY, c1 = -INFINITY, c2 = -INFINITY;
    for (int p0 = rs; p0 < re; p0 += 64) {
        int p = p0 + lane;
        bool act = p < re;
        int d = act ? dsts_s[p] : 0;
        float t0 = act ? leaky(el0 + er[d * 3 + 0]) : -INFINITY;
        float t1 = act ? leaky(el1 + er[d * 3 + 1]) : -INFINITY;
        float t2 = act ? leaky(el2 + er[d * 3 + 2]) : -INFINITY;
        if (single) { c0 = t0; c1 = t1; c2 = t2; }
        m0 = fmaxf(m0, t0); m1 = fmaxf(m1, t1); m2 = fmaxf(m2, t2);
    }
#pragma unroll
    for (int off = 1; off < 64; off <<= 1) {
        m0 = fmaxf(m0, __shfl_xor(m0, off));
        m1 = fmaxf(m1, __shfl_xor(m1, off));
        m2 = fmaxf(m2, __shfl_xor(m2, off));
    }
    float s0 = 0, s1 = 0, s2 = 0;
    if (single) {
        bool act = (rs + lane) < re;
        s0 = act ? expf(c0 - m0) : 0.f;
        s1 = act ? expf(c1 - m1) : 0.f;
        s2 = act ? expf(c2 - m2) : 0.f;
    } else {
        for (int p0 = rs; p0 < re; p0 += 64) {
            int p = p0 + lane;
            if (p < re) {
                int d = dsts_s[p];
                s0 += expf(leaky(el0 + er[d * 3 + 0]) - m0);
                s1 += expf(leaky(el1 + er[d * 3 + 1]) - m1);
                s2 += expf(leaky(el2 + er[d * 3 + 2]) - m2);
            }
        }
    }
#pragma unroll
    for (int off = 1; off < 64; off <<= 1) {
        s0 += __shfl_xor(s0, off);
        s1 += __shfl_xor(s1, off);
        s2 += __shfl_xor(s2, off);
    }
    if (lane == 0) {
        mssrc[n * 3 + 0] = make_float2(m0, s0);
        mssrc[n * 3 + 1] = make_float2(m1, s1);
        mssrc[n * 3 + 2] = make_float2(m2, s2);
    }
}

// -------- dst-side stats + fused symmetric attention coefficient ----------
__global__ __launch_bounds__(256) void k_seg_dst_attn(const int* __restrict__ srcs_d,
                                                      const int* __restrict__ rows_d,
                                                      const float* __restrict__ el,
                                                      const float* __restrict__ er,
                                                      const float2* __restrict__ mssrc,
                                                      float* __restrict__ a_sorted) {
    int wid = threadIdx.x >> 6, lane = threadIdx.x & 63;
    int n = blockIdx.x * 4 + wid;
    if (n >= N_NODES) return;
    int rs = rows_d[n], re = rows_d[n + 1];
    if (rs >= re) return;
    float er0 = er[n * 3 + 0], er1 = er[n * 3 + 1], er2 = er[n * 3 + 2];
    bool single = (re - rs) <= 64;
    float m0 = -INFINITY, m1 = -INFINITY, m2 = -INFINITY;
    float c0 = -INFINITY, c1 = -INFINITY, c2 = -INFINITY;
    int scache = 0;
    for (int p0 = rs; p0 < re; p0 += 64) {
        int p = p0 + lane;
        bool act = p < re;
        int s = act ? srcs_d[p] : 0;
        if (single) scache = s;
        float t0 = act ? leaky(el[s * 3 + 0] + er0) : -INFINITY;
        float t1 = act ? leaky(el[s * 3 + 1] + er1) : -INFINITY;
        float t2 = act ? leaky(el[s * 3 + 2] + er2) : -INFINITY;
        if (single) { c0 = t0; c1 = t1; c2 = t2; }
        m0 = fmaxf(m0, t0); m1 = fmaxf(m1, t1); m2 = fmaxf(m2, t2);
    }
#pragma unroll
    for (int off = 1; off < 64; off <<= 1) {
        m0 = fmaxf(m0, __shfl_xor(m0, off));
        m1 = fmaxf(m1, __shfl_xor(m1, off));
        m2 = fmaxf(m2, __shfl_xor(m2, off));
    }
    float s0 = 0, s1 = 0, s2 = 0;
    if (single) {
        bool act = (rs + lane) < re;
        s0 = act ? expf(c0 - m0) : 0.f;
        s1 = act ? expf(c1 - m1) : 0.f;
        s2 = act ? expf(c2 - m2) : 0.f;
    } else {
        for (int p0 = rs; p0 < re; p0 += 64) {
            int p = p0 + lane;
            if (p < re) {
                int s = srcs_d[p];
                s0 += expf(leaky(el[s * 3 + 0] + er0) - m0);
                s1 += expf(leaky(el[s * 3 + 1] + er1) - m1);
                s2 += expf(leaky(el[s * 3 + 2] + er2) - m2);
            }
        }
    }
#pragma unroll
    for (int off = 1; off < 64; off <<= 1) {
        s0 += __shfl_xor(s0, off);
        s1 += __shfl_xor(s1, off);
        s2 += __shfl_xor(s2, off);
    }
    float i0 = 1.f / s0, i1 = 1.f / s1, i2 = 1.f / s2;
    for (int p0 = rs; p0 < re; p0 += 64) {
        int p = p0 + lane;
        if (p >= re) break;
        int s = single ? scache : srcs_d[p];
        float t0, t1, t2;
        if (single) { t0 = c0; t1 = c1; t2 = c2; }
        else {
            t0 = leaky(el[s * 3 + 0] + er0);
            t1 = leaky(el[s * 3 + 1] + er1);
            t2 = leaky(el[s * 3 + 2] + er2);
        }
        float2 a0 = mssrc[s * 3 + 0], a1 = mssrc[s * 3 + 1], a2 = mssrc[s * 3 + 2];
        float d0 = fmaxf(expf(t0 - m0) * i0, EPS_V);
        float d1 = fmaxf(expf(t1 - m1) * i1, EPS_V);
        float d2 = fmaxf(expf(t2 - m2) * i2, EPS_V);
        float u0 = fmaxf(expf(t0 - a0.x) / a0.y, EPS_V);
        float u1 = fmaxf(expf(t1 - a1.x) / a1.y, EPS_V);
        float u2 = fmaxf(expf(t2 - a2.x) / a2.y, EPS_V);
        a_sorted[p * 3 + 0] = sqrtf(d0 * u0);
        a_sorted[p * 3 + 1] = sqrtf(d1 * u1);
        a_sorted[p * 3 + 2] = sqrtf(d2 * u2);
    }
}

// ------- one diffusion hop: 8-deep software-pipelined gather (bf16, f32 accum) -------
__global__ __launch_bounds__(256) void k_hop(const bf16* __restrict__ cur,
                                             const float* __restrict__ a_sorted,
                                             const int* __restrict__ rowstart,
                                             const int* __restrict__ src_sorted,
                                             bf16* __restrict__ out) {
    int wid = threadIdx.x >> 6, lane = threadIdx.x & 63;
    int n = blockIdx.x * 4 + wid;
    if (n >= N_NODES) return;
    if (lane >= HD) return;
    int h = lane >> 4;
    int rs = rowstart[n], re = rowstart[n + 1];
    float acc = 0.f;
    int p = rs;
    for (; p + 8 <= re; p += 8) {
        int s[8];
#pragma unroll
        for (int j = 0; j < 8; ++j) s[j] = src_sorted[p + j];
        float a[8];
#pragma unroll
        for (int j = 0; j < 8; ++j) a[j] = a_sorted[(p + j) * HH + h];
        float v[8];
#pragma unroll
        for (int j = 0; j < 8; ++j) v[j] = b2f(cur[s[j] * HD + lane]);
#pragma unroll
        for (int j = 0; j < 8; ++j) acc += a[j] * v[j];
    }
    if (p < re) {
        int cnt = re - p;
        int s[8];
#pragma unroll
        for (int j = 0; j < 8; ++j) s[j] = (j < cnt) ? src_sorted[p + j] : 0;
        float a[8];
#pragma unroll
        for (int j = 0; j < 8; ++j) a[j] = (j < cnt) ? a_sorted[(p + j) * HH + h] : 0.f;
        float v[8];
#pragma unroll
        for (int j = 0; j < 8; ++j) v[j] = (j < cnt) ? b2f(cur[s[j] * HD + lane]) : 0.f;
#pragma unroll
        for (int j = 0; j < 8; ++j) acc += a[j] * v[j];
    }
    out[n * HD + lane] = __float2bfloat16(acc);
}

// ---------------- feat_trans + hop attention + output ----------------
__global__ void k_final(const float* __restrict__ ft, const bf16* __restrict__ cur1,
                        const bf16* __restrict__ cur2, const bf16* __restrict__ cur3,
                        const float* __restrict__ hop_l, const float* __restrict__ hop_r,
                        const float* __restrict__ pos_emb, const float* __restrict__ scales,
                        const float* __restrict__ offs, const float* __restrict__ bias,
                        float* __restrict__ out) {
    int i = blockIdx.x * blockDim.x + threadIdx.x;
    if (i >= N_NODES * HH) return;
    int h = i % HH;
    float hk[4][DD];
#pragma unroll
    for (int k = 0; k < 4; ++k) {
        float x[DD];
#pragma unroll
        for (int d = 0; d < DD; ++d) {
            x[d] = (k == 0) ? ft[(size_t)i * DD + d]
                 : (k == 1) ? b2f(cur1[(size_t)i * DD + d])
                 : (k == 2) ? b2f(cur2[(size_t)i * DD + d])
                            : b2f(cur3[(size_t)i * DD + d]);
        }
        float m = 0.f;
#pragma unroll
        for (int d = 0; d < DD; ++d) m += x[d];
        m *= (1.f / DD);
        float v2 = 0.f;
#pragma unroll
        for (int d = 0; d < DD; ++d) {
            float c = x[d] - m;
            v2 += c * c;
        }
        v2 = v2 * (1.f / DD) + EPS_V;
        float rsq = rsqrtf(v2);
#pragma unroll
        for (int d = 0; d < DD; ++d) {
            hk[k][d] = (x[d] - m) * scales[k * HD + h * DD + d] * rsq +
                       offs[k * HD + h * DD + d] + pos_emb[h * 64 + k * DD + d];
        }
    }
    float al = 0.f;
#pragma unroll
    for (int d = 0; d < DD; ++d) al += hk[0][d] * hop_l[h * DD + d];
    float ar[3], mx = -1e30f;
#pragma unroll
    for (int k = 0; k < 3; ++k) {
        float s = 0.f;
#pragma unroll
        for (int d = 0; d < DD; ++d) s += hk[k + 1][d] * hop_r[h * DD + d];
        ar[k] = leaky(s + al);
        mx = fmaxf(mx, ar[k]);
    }
    float den = 0.f, wgt[3];
#pragma unroll
    for (int k = 0; k < 3; ++k) {
        wgt[k] = expf(ar[k] - mx);
        den += wgt[k];
    }
#pragma unroll
    for (int k = 0; k < 3; ++k) wgt[k] /= den;
#pragma unroll
    for (int d = 0; d < DD; ++d) {
        float o = hk[1][d] * wgt[0] + hk[2][d] * wgt[1] + hk[3][d] * wgt[2] +
                  bias[h * DD + d];
        out[i * DD + d] = o;
    }
}

// ---------------- workspace layout (4B-element offsets) ----------------
#define OFF_FT     0u          // 4.8M f32
#define OFF_FT16   4800000u    // 2.4M slots (bf16 x 4.8M)
#define OFF_EL     7200000u    // 300k
#define OFF_ER     7500000u    // 300k
#define OFF_MSSRC  7800000u    // 600k (float2 x 300k)
#define OFF_BCNT   8400000u    // 1600: bcnt_d@0, bcnt_s@400, bfill_d@800, bfill_s@1200 [memset]
#define OFF_BBASE  8401600u    // 800: bbase_d@0 (NB+1), bbase_s@400
#define OFF_ROWD   8402400u    // 100001
#define OFF_ROWS_  8502402u    // 100001
#define OFF_BKTD   8602404u    // 1.6M u32
#define OFF_BKTS   10202404u   // 1.6M u32
#define OFF_SRCSD  11802404u   // 1.6M
#define OFF_DSTSS  13402404u   // 1.6M
#define OFF_ASORT  15002404u   // 4.8M
#define OFF_CUR1   19802404u   // 2.4M slots
#define OFF_CUR2   22202404u
#define OFF_CUR3   24602404u
#define WS_FLOATS  27002404u   // ~108 MB

extern "C" void kernel_launch(void* const* d_in, const int* in_sizes, int n_in,
                              void* d_out, int out_size, void* d_ws, size_t ws_size,
                              hipStream_t stream) {
    if (ws_size < (size_t)WS_FLOATS * 4) return;

    const float* feat   = (const float*)d_in[0];
    const int*   src    = (const int*)d_in[1];
    const int*   dst    = (const int*)d_in[2];
    const float* fc_W   = (const float*)d_in[3];
    const float* attn_l = (const float*)d_in[4];
    const float* attn_r = (const float*)d_in[5];
    const float* hop_l  = (const float*)d_in[6];
    const float* hop_r  = (const float*)d_in[7];
    const float* pos    = (const float*)d_in[8];
    const float* scal   = (const float*)d_in[9];
    const float* offs   = (const float*)d_in[10];
    const float* bias   = (const float*)d_in[11];
    float* out = (float*)d_out;

    float* ws = (float*)d_ws;
    float*    ft      = ws + OFF_FT;
    bf16*     ft16    = (bf16*)(ws + OFF_FT16);
    float*    el      = ws + OFF_EL;
    float*    er      = ws + OFF_ER;
    float2*   mssrc   = (float2*)(ws + OFF_MSSRC);
    int*      bcnt_d  = (int*)(ws + OFF_BCNT);
    int*      bcnt_s  = bcnt_d + 400;
    int*      bfill_d = bcnt_d + 800;
    int*      bfill_s = bcnt_d + 1200;
    int*      bbase_d = (int*)(ws + OFF_BBASE);
    int*      bbase_s = bbase_d + 400;
    int*      rows_d  = (int*)(ws + OFF_ROWD);
    int*      rows_s  = (int*)(ws + OFF_ROWS_);
    unsigned* bkt_d   = (unsigned*)(ws + OFF_BKTD);
    unsigned* bkt_s   = (unsigned*)(ws + OFF_BKTS);
    int*      srcs_d  = (int*)(ws + OFF_SRCSD);
    int*      dsts_s  = (int*)(ws + OFF_DSTSS);
    float*    a_sorted= ws + OFF_ASORT;
    bf16*     cur1    = (bf16*)(ws + OFF_CUR1);
    bf16*     cur2    = (bf16*)(ws + OFF_CUR2);
    bf16*     cur3    = (bf16*)(ws + OFF_CUR3);

    hipMemsetAsync(ws + OFF_BCNT, 0, 1600 * 4, stream);

    k_gemm<<<(N_NODES + 255) / 256, 256, 0, stream>>>(feat, fc_W, ft, ft16);
    k_eler<<<(N_NODES * HH + 255) / 256, 256, 0, stream>>>(ft, attn_l, attn_r, el, er);

    k_bhist<<<400, 256, 0, stream>>>((const int4*)src, (const int4*)dst, bcnt_s, bcnt_d);
    k_bscan<<<2, 512, 0, stream>>>(bcnt_d, bbase_d, bcnt_s, bbase_s, rows_d, rows_s);
    k_msplit<<<(N_EDGES + MS_T - 1) / MS_T, 256, 0, stream>>>(src, dst, bbase_d, bbase_s,
                                                              bfill_d, bfill_s, bkt_d, bkt_s);
    k_bfinal<<<NB, 256, 0, stream>>>(bkt_d, bbase_d, rows_d, srcs_d);
    k_bfinal<<<NB, 256, 0, stream>>>(bkt_s, bbase_s, rows_s, dsts_s);

    k_seg_src<<<(N_NODES + 3) / 4, 256, 0, stream>>>(dsts_s, rows_s, el, er, mssrc);
    k_seg_dst_attn<<<(N_NODES + 3) / 4, 256, 0, stream>>>(srcs_d, rows_d, el, er,
                                                          mssrc, a_sorted);
    k_hop<<<(N_NODES + 3) / 4, 256, 0, stream>>>(ft16, a_sorted, rows_d, srcs_d, cur1);
    k_hop<<<(N_NODES + 3) / 4, 256, 0, stream>>>(cur1, a_sorted, rows_d, srcs_d, cur2);
    k_hop<<<(N_NODES + 3) / 4, 256, 0, stream>>>(cur2, a_sorted, rows_d, srcs_d, cur3);
    k_final<<<(N_NODES * HH + 255) / 256, 256, 0, stream>>>(ft, cur1, cur2, cur3, hop_l,
                                                            hop_r, pos, scal, offs, bias,
                                                            out);
}